// Round 3
// baseline (3007.182 us; speedup 1.0000x reference)
//
#include <hip/hip_runtime.h>
#include <hip/hip_fp16.h>

// RGCN 3-layer, aggregate-first fused:
//   h[n] = relu( sum_r mean_r[n] @ W_r + x[n] @ W_root + b ),  mean from L3-resident x
// Edges counting-sorted by (relation, dst); fused kernel: per 128-node tile,
// per relation: edge-parallel gather -> LDS fp32 atomic accumulate -> MFMA,
// accumulating all 9 matmuls in registers. Layer 3 only at root rows.

typedef _Float16 f16;
typedef _Float16 f16x2 __attribute__((ext_vector_type(2)));
typedef _Float16 f16x4 __attribute__((ext_vector_type(4)));
typedef _Float16 f16x8 __attribute__((ext_vector_type(8)));
typedef float f32x4 __attribute__((ext_vector_type(4)));

#define NREL 8

// ---------------- setup kernels ----------------
__global__ void k_hist(const int* __restrict__ dst, const int* __restrict__ et,
                       int E, int N, int* __restrict__ cnt) {
  int e = blockIdx.x * 256 + threadIdx.x;
  if (e < E) atomicAdd(&cnt[et[e] * N + dst[e]], 1);
}

__global__ void k_scan1(const int* __restrict__ in, int* __restrict__ out,
                        int* __restrict__ part, int n) {
  __shared__ int sh[256];
  int b = blockIdx.x, t = threadIdx.x;
  int base = b * 4096 + t * 16;
  int v[16]; int s = 0;
#pragma unroll
  for (int j = 0; j < 16; j++) { int idx = base + j; int x = (idx < n) ? in[idx] : 0; v[j] = s; s += x; }
  sh[t] = s; __syncthreads();
  for (int off = 1; off < 256; off <<= 1) {
    int x = 0; if (t >= off) x = sh[t - off];
    __syncthreads();
    if (t >= off) sh[t] += x;
    __syncthreads();
  }
  int excl = (t == 0) ? 0 : sh[t - 1];
  if (t == 255) part[b] = sh[255];
#pragma unroll
  for (int j = 0; j < 16; j++) { int idx = base + j; if (idx < n) out[idx] = v[j] + excl; }
}

__global__ void k_scan2(int* __restrict__ part, int nb) {  // nb <= 256, 1 block
  __shared__ int sh[256];
  int t = threadIdx.x;
  sh[t] = (t < nb) ? part[t] : 0; __syncthreads();
  for (int off = 1; off < 256; off <<= 1) {
    int x = 0; if (t >= off) x = sh[t - off];
    __syncthreads();
    if (t >= off) sh[t] += x;
    __syncthreads();
  }
  if (t < nb) part[t] = (t == 0) ? 0 : sh[t - 1];
}

__global__ void k_scan3(int* __restrict__ out, const int* __restrict__ part, int n) {
  int i = blockIdx.x * 256 + threadIdx.x;
  if (i < n) out[i] += part[i >> 12];
}

__global__ void k_sentinel(int* __restrict__ p, int v) { *p = v; }

__global__ void k_sinv(const int* __restrict__ cnt, float* __restrict__ sinv, int n) {
  int i = blockIdx.x * 256 + threadIdx.x;
  if (i < n) { int c = cnt[i]; sinv[i] = 1.0f / (float)(c > 1 ? c : 1); }
}

__global__ void k_scatter(const int* __restrict__ src, const int* __restrict__ dstv,
                          const int* __restrict__ et, int E, int N,
                          const int* __restrict__ off_rn, int* __restrict__ fill,
                          int* __restrict__ sps2) {
  int e = blockIdx.x * 256 + threadIdx.x;
  if (e >= E) return;
  int d = dstv[e];
  int key = et[e] * N + d;
  int pos = off_rn[key] + atomicAdd(&fill[key], 1);
  sps2[pos] = src[e] | ((d & 127) << 20);   // src < 2^20, dst_local in bits 20..26
}

__global__ void k_f32_to_f16(const float* __restrict__ in, f16* __restrict__ out, int n4) {
  int i = blockIdx.x * 256 + threadIdx.x;
  if (i < n4) {
    float4 v = ((const float4*)in)[i];
    f16x4 o; o[0] = (f16)v.x; o[1] = (f16)v.y; o[2] = (f16)v.z; o[3] = (f16)v.w;
    ((f16x4*)out)[i] = o;
  }
}

// transpose 9 weight chunks: 0..7 from wrel[r][k][h], 8 from wroot[k][h]
// -> Wt[(c*128+h)*128 + k] f16
__global__ void k_tpw9(const float* __restrict__ wrel, const float* __restrict__ wroot,
                       f16* __restrict__ dst) {
  int h = blockIdx.x, c = blockIdx.y, k = threadIdx.x;
  float v = (c < 8) ? wrel[(size_t)c * 16384 + k * 128 + h] : wroot[k * 128 + h];
  dst[(size_t)(c * 128 + h) * 128 + k] = (f16)v;
}

// ---------------- fused layer: aggregate + 9 matmuls + bias + relu ----------------
// grid: (N+127)/128 blocks, 256 threads (4 waves, 2x2 over 128x128 out tile)
__global__ __launch_bounds__(256, 2) void k_layer(
    const f16* __restrict__ Xin, const int* __restrict__ sps2,
    const int* __restrict__ off_rn, const float* __restrict__ sinv_rn,
    const f16* __restrict__ Wt, const float* __restrict__ bias,
    f16* __restrict__ hout, int N) {
  __shared__ float A32[128 * 132];   // perm layout: col c at p = c/2 + (c&1)*64
  __shared__ float sinv_s[128];
  __shared__ float bias_s[128];
  int tid = threadIdx.x;
  int n0 = blockIdx.x * 128;
  int nend = n0 + 128 < N ? n0 + 128 : N;
  int w = tid >> 6, l = tid & 63;
  int lm = l & 15, lk = l >> 4;
  int wm = (w & 1) * 64, wn = (w >> 1) * 64;
  if (tid < 128) bias_s[tid] = bias[tid];
  f32x4 acc[4][4] = {};

  for (int r = 0; r < NREL; r++) {
    __syncthreads();   // A32 free (prev mfma reads done)
    {
      f32x4 zz = {0.f, 0.f, 0.f, 0.f};
      for (int i = tid; i < 128 * 132 / 4; i += 256) ((f32x4*)A32)[i] = zz;
    }
    if (tid < 128)
      sinv_s[tid] = (n0 + tid < N) ? sinv_rn[(size_t)r * N + n0 + tid] : 0.f;
    __syncthreads();
    int e0 = off_rn[r * N + n0];
    int e1 = off_rn[r * N + nend];
    // edge-parallel gather: wave w takes edges e0+w, e0+w+4, ... ; 8-deep batches
    int e = e0 + w;
    while (e + 28 < e1) {
      int ps[8];
#pragma unroll
      for (int u = 0; u < 8; u++) ps[u] = sps2[e + u * 4];
      f16x2 xv[8];
#pragma unroll
      for (int u = 0; u < 8; u++)
        xv[u] = *(const f16x2*)(Xin + (size_t)(ps[u] & 0xFFFFF) * 128 + l * 2);
#pragma unroll
      for (int u = 0; u < 8; u++) {
        int dl = ((unsigned)ps[u]) >> 20;
        float sc = sinv_s[dl];
        atomicAdd(&A32[dl * 132 + l], (float)xv[u][0] * sc);
        atomicAdd(&A32[dl * 132 + 64 + l], (float)xv[u][1] * sc);
      }
      e += 32;
    }
    for (; e < e1; e += 4) {
      int ps = sps2[e];
      f16x2 xv = *(const f16x2*)(Xin + (size_t)(ps & 0xFFFFF) * 128 + l * 2);
      int dl = ((unsigned)ps) >> 20;
      float sc = sinv_s[dl];
      atomicAdd(&A32[dl * 132 + l], (float)xv[0] * sc);
      atomicAdd(&A32[dl * 132 + 64 + l], (float)xv[1] * sc);
    }
    __syncthreads();
    // MFMA: A from LDS fp32 (perm), B from global (L2-hot)
#pragma unroll
    for (int ks = 0; ks < 4; ks++) {
      int hk = ks * 16 + lk * 4;
      f16x8 a[4], b[4];
#pragma unroll
      for (int i = 0; i < 4; i++) {
        int row = wm + i * 16 + lm;
        f32x4 r1 = *(const f32x4*)&A32[row * 132 + hk];
        f32x4 r2 = *(const f32x4*)&A32[row * 132 + 64 + hk];
        f16x8 fr;
        fr[0] = (f16)r1[0]; fr[1] = (f16)r2[0]; fr[2] = (f16)r1[1]; fr[3] = (f16)r2[1];
        fr[4] = (f16)r1[2]; fr[5] = (f16)r2[2]; fr[6] = (f16)r1[3]; fr[7] = (f16)r2[3];
        a[i] = fr;
      }
#pragma unroll
      for (int j = 0; j < 4; j++)
        b[j] = *(const f16x8*)(Wt + ((size_t)r * 128 + wn + j * 16 + lm) * 128 + ks * 32 + lk * 8);
#pragma unroll
      for (int i = 0; i < 4; i++)
#pragma unroll
        for (int j = 0; j < 4; j++)
          acc[i][j] = __builtin_amdgcn_mfma_f32_16x16x32_f16(a[i], b[j], acc[i][j], 0, 0, 0);
    }
  }

  // root term: A = Xin tile directly
#pragma unroll
  for (int ks = 0; ks < 4; ks++) {
    f16x8 a[4], b[4];
#pragma unroll
    for (int i = 0; i < 4; i++) {
      int row = n0 + wm + i * 16 + lm;
      f16x8 z = {(f16)0, (f16)0, (f16)0, (f16)0, (f16)0, (f16)0, (f16)0, (f16)0};
      a[i] = (row < N) ? *(const f16x8*)(Xin + (size_t)row * 128 + ks * 32 + lk * 8) : z;
    }
#pragma unroll
    for (int j = 0; j < 4; j++)
      b[j] = *(const f16x8*)(Wt + ((size_t)8 * 128 + wn + j * 16 + lm) * 128 + ks * 32 + lk * 8);
#pragma unroll
    for (int i = 0; i < 4; i++)
#pragma unroll
      for (int j = 0; j < 4; j++)
        acc[i][j] = __builtin_amdgcn_mfma_f32_16x16x32_f16(a[i], b[j], acc[i][j], 0, 0, 0);
  }

  // epilogue: bias + relu, repack through LDS for coalesced f16 store
  __syncthreads();
  f16* H = (f16*)A32;   // [128][136]
#pragma unroll
  for (int i = 0; i < 4; i++)
#pragma unroll
    for (int j = 0; j < 4; j++)
#pragma unroll
      for (int q = 0; q < 4; q++) {
        int row = wm + i * 16 + lk * 4 + q;
        int col = wn + j * 16 + lm;
        float v = acc[i][j][q] + bias_s[col];
        H[row * 136 + col] = (f16)fmaxf(v, 0.f);
      }
  __syncthreads();
  for (int i = tid; i < 128 * 16; i += 256) {
    int row = i >> 4, c8 = i & 15;
    if (n0 + row < N)
      *(f16x8*)(hout + (size_t)(n0 + row) * 128 + c8 * 8) =
          *(const f16x8*)(H + row * 136 + c8 * 8);
  }
}

// ---------------- layer 3: only at root rows, weights in LDS ----------------
__global__ __launch_bounds__(128) void k_layer3(const f16* __restrict__ h2,
                                                const int* __restrict__ sps2,
                                                const int* __restrict__ off_rn,
                                                const float* __restrict__ sinv_rn,
                                                const int* __restrict__ ridx,
                                                const float* __restrict__ wrel,
                                                const float* __restrict__ wroot,
                                                const float* __restrict__ b3,
                                                float* __restrict__ out, int N) {
  __shared__ f16 W[9 * 2048];   // 0..7 = wrel3[r][k][c], 8 = root3[k][c]
  __shared__ float red[2][16];
  __shared__ float sinv_s[8];
  int t = threadIdx.x;
  int n = ridx[blockIdx.x];
  for (int j = t; j < 9 * 2048; j += 128)
    W[j] = (f16)((j < 8 * 2048) ? wrel[j] : wroot[j - 8 * 2048]);
  if (t < 8) sinv_s[t] = sinv_rn[(size_t)t * N + n];
  __syncthreads();
  int c = t & 15, kg = t >> 4;   // 8 k-groups of 16
  float a = 0.f;
  for (int r = 0; r < NREL; r++) {
    int e0 = off_rn[r * N + n], e1 = off_rn[r * N + n + 1];
    float sc = sinv_s[r];
    for (int e = e0; e < e1; e++) {
      int s = sps2[e] & 0xFFFFF;
      float p = 0.f;
#pragma unroll
      for (int j = 0; j < 16; j++) {
        int k = kg * 16 + j;
        p += (float)h2[(size_t)s * 128 + k] * (float)W[r * 2048 + k * 16 + c];
      }
      a += sc * p;
    }
  }
  {
    float p = 0.f;
#pragma unroll
    for (int j = 0; j < 16; j++) {
      int k = kg * 16 + j;
      p += (float)h2[(size_t)n * 128 + k] * (float)W[8 * 2048 + k * 16 + c];
    }
    a += p;
  }
  a += __shfl_xor(a, 16);
  a += __shfl_xor(a, 32);
  if ((t & 63) < 16) red[t >> 6][t & 15] = a;
  __syncthreads();
  if (t < 16) out[(size_t)blockIdx.x * 16 + t] = red[0][t] + red[1][t] + b3[t];
}

// ---------------- host ----------------
extern "C" void kernel_launch(void* const* d_in, const int* in_sizes, int n_in,
                              void* d_out, int out_size, void* d_ws, size_t ws_size,
                              hipStream_t stream) {
  const float* x     = (const float*)d_in[0];
  const int*   eidx  = (const int*)d_in[1];
  const int*   etyp  = (const int*)d_in[2];
  const int*   ridx  = (const int*)d_in[3];
  const float* wrel1 = (const float*)d_in[4];
  const float* root1 = (const float*)d_in[5];
  const float* b1    = (const float*)d_in[6];
  const float* wrel2 = (const float*)d_in[7];
  const float* root2 = (const float*)d_in[8];
  const float* b2    = (const float*)d_in[9];
  const float* wrel3 = (const float*)d_in[10];
  const float* root3 = (const float*)d_in[11];
  const float* b3    = (const float*)d_in[12];

  int N = in_sizes[0] / 128;
  int E = in_sizes[2];
  int NROOT = in_sizes[3];
  const int* esrc = eidx;
  const int* edst = eidx + E;
  int NR = NREL * N;   // 800K bins

  char* p = (char*)d_ws;
  auto alloc = [&](size_t bytes) { void* r = (void*)p; p += (bytes + 255) & ~(size_t)255; return r; };
  int*   cnt_rn  = (int*)alloc((size_t)NR * 4);
  int*   off_rn  = (int*)alloc((size_t)(NR + 1) * 4);
  int*   fill    = (int*)alloc((size_t)NR * 4);
  float* sinv_rn = (float*)alloc((size_t)NR * 4);
  int*   part    = (int*)alloc(4096 * 4);
  int*   sps2    = (int*)alloc((size_t)E * 4);
  f16*   Xh      = (f16*)alloc((size_t)N * 128 * 2);   // reused as h2
  f16*   h1      = (f16*)alloc((size_t)N * 128 * 2);
  f16*   Wt      = (f16*)alloc((size_t)9 * 128 * 128 * 2);
  f16*   h2      = Xh;   // alias: Xh dead after layer-1

  int eb = (E + 255) / 256;
  hipMemsetAsync(cnt_rn, 0, (size_t)NR * 4, stream);
  hipMemsetAsync(fill, 0, (size_t)NR * 4, stream);
  k_hist<<<eb, 256, 0, stream>>>(edst, etyp, E, N, cnt_rn);
  int nb1 = (NR + 4095) / 4096;   // 196
  k_scan1<<<nb1, 256, 0, stream>>>(cnt_rn, off_rn, part, NR);
  k_scan2<<<1, 256, 0, stream>>>(part, nb1);
  k_scan3<<<(NR + 255) / 256, 256, 0, stream>>>(off_rn, part, NR);
  k_sentinel<<<1, 1, 0, stream>>>(off_rn + NR, E);
  k_sinv<<<(NR + 255) / 256, 256, 0, stream>>>(cnt_rn, sinv_rn, NR);
  k_scatter<<<eb, 256, 0, stream>>>(esrc, edst, etyp, E, N, off_rn, fill, sps2);
  k_f32_to_f16<<<((N * 32) + 255) / 256, 256, 0, stream>>>(x, Xh, N * 32);

  int mb = (N + 127) / 128;
  k_tpw9<<<dim3(128, 9), 128, 0, stream>>>(wrel1, root1, Wt);
  k_layer<<<mb, 256, 0, stream>>>(Xh, sps2, off_rn, sinv_rn, Wt, b1, h1, N);
  k_tpw9<<<dim3(128, 9), 128, 0, stream>>>(wrel2, root2, Wt);
  k_layer<<<mb, 256, 0, stream>>>(h1, sps2, off_rn, sinv_rn, Wt, b2, h2, N);
  k_layer3<<<NROOT, 128, 0, stream>>>(h2, sps2, off_rn, sinv_rn, ridx, wrel3, root3,
                                      b3, (float*)d_out, N);
}

// Round 5
// 749.576 us; speedup vs baseline: 4.0118x; 4.0118x over previous
//
#include <hip/hip_runtime.h>
#include <hip/hip_fp16.h>

// RGCN 3-layer, transform-first with column-split passes:
//   Y = A @ [W_0..W_7, W_root] restricted to output cols [p*PW,(p+1)*PW)
//   h[n, cols] = relu( Y[n,rootblk] + sum_e (1/cnt[n,ty]) * Y[src_e, ty-blk] + bias )
// Edges counting-sorted by dst (payload src|type<<20); per-node type counts
// computed on the fly (int LDS atomics, native). Layer-2 edge pass pruned to
// nodes layer-3 reads. Layer 3 only at root rows. All matmuls fp16 MFMA.

typedef _Float16 f16;
typedef _Float16 f16x8 __attribute__((ext_vector_type(8)));
typedef float f32x4 __attribute__((ext_vector_type(4)));

#define NREL 8

// ---------------- setup kernels ----------------
__global__ void k_hist(const int* __restrict__ dst, int E, int* __restrict__ cnt) {
  int e = blockIdx.x * 256 + threadIdx.x;
  if (e < E) atomicAdd(&cnt[dst[e]], 1);
}

// exclusive scan pass 1 (in-place safe: each block reads then writes only its range)
__global__ void k_scan1(const int* __restrict__ in, int* __restrict__ out,
                        int* __restrict__ part, int n) {
  __shared__ int sh[256];
  int b = blockIdx.x, t = threadIdx.x;
  int base = b * 4096 + t * 16;
  int v[16]; int s = 0;
#pragma unroll
  for (int j = 0; j < 16; j++) { int idx = base + j; int x = (idx < n) ? in[idx] : 0; v[j] = s; s += x; }
  sh[t] = s; __syncthreads();
  for (int off = 1; off < 256; off <<= 1) {
    int x = 0; if (t >= off) x = sh[t - off];
    __syncthreads();
    if (t >= off) sh[t] += x;
    __syncthreads();
  }
  int excl = (t == 0) ? 0 : sh[t - 1];
  if (t == 255) part[b] = sh[255];
#pragma unroll
  for (int j = 0; j < 16; j++) { int idx = base + j; if (idx < n) out[idx] = v[j] + excl; }
}

__global__ void k_scan2(int* __restrict__ part, int nb) {  // nb <= 256, 1 block
  __shared__ int sh[256];
  int t = threadIdx.x;
  sh[t] = (t < nb) ? part[t] : 0; __syncthreads();
  for (int off = 1; off < 256; off <<= 1) {
    int x = 0; if (t >= off) x = sh[t - off];
    __syncthreads();
    if (t >= off) sh[t] += x;
    __syncthreads();
  }
  if (t < nb) part[t] = (t == 0) ? 0 : sh[t - 1];
}

__global__ void k_scan3(int* __restrict__ out, const int* __restrict__ part, int n) {
  int i = blockIdx.x * 256 + threadIdx.x;
  if (i < n) out[i] += part[i >> 12];
}

__global__ void k_sentinel(int* __restrict__ p, int v) { *p = v; }

__global__ void k_scatter(const int* __restrict__ src, const int* __restrict__ dstv,
                          const int* __restrict__ et, int E,
                          const int* __restrict__ off, int* __restrict__ fill,
                          int* __restrict__ sps) {
  int e = blockIdx.x * 256 + threadIdx.x;
  if (e >= E) return;
  int d = dstv[e];
  int pos = off[d] + atomicAdd(&fill[d], 1);
  sps[pos] = src[e] | (et[e] << 20);   // src < 2^20, type in bits 20..23
}

// mark nodes whose h2 is read by layer 3: roots + src of root in-edges
__global__ void k_mark(const int* __restrict__ ridx, const int* __restrict__ off,
                       const int* __restrict__ sps, int* __restrict__ mark) {
  int i = blockIdx.x, t = threadIdx.x;
  int n = ridx[i];
  if (t == 0) mark[n] = 1;
  int e0 = off[n], e1 = off[n + 1];
  for (int e = e0 + t; e < e1; e += 64) mark[sps[e] & 0xFFFFF] = 1;
}

// weights for pass p: Wt[row][k], row = cb*PW + j -> source col p*PW+j of chunk cb
// (cb 0..7 = wrel[cb][k][col], cb 8 = wroot[k][col]); pad rows (>= 9*PW) zero.
__global__ void k_tpw(const float* __restrict__ wrel, const float* __restrict__ wroot,
                      f16* __restrict__ dst, int PW, int p) {
  int row = blockIdx.x, k = threadIdx.x;
  float v = 0.f;
  if (row < 9 * PW) {
    int cb = row / PW, j = row - cb * PW;
    int col = p * PW + j;
    v = (cb < 8) ? wrel[(size_t)cb * 16384 + k * 128 + col] : wroot[k * 128 + col];
  }
  dst[(size_t)row * 128 + k] = (f16)v;
}

// ---------------- GEMM: C[M x ncol] = A[M x 128] * Bt^T, Bt is [>=ncol][128] f16 ----
// A is f16 or f32 (converted in staging).
template <typename AT>
__global__ __launch_bounds__(256) void k_gemm(const AT* __restrict__ A,
                                              const f16* __restrict__ Bt,
                                              f16* __restrict__ C, int M, int ncol) {
  __shared__ f16 As[128 * 136];
  __shared__ f16 Bs[128 * 136];
  int m0 = blockIdx.x * 128, n0 = blockIdx.y * 128;
  int tid = threadIdx.x;
#pragma unroll
  for (int cch = 0; cch < 8; cch++) {
    int ci = tid + cch * 256;       // 0..2047, 8 elems each
    int row = ci >> 4, c8 = ci & 15;
    int gm = m0 + row;
    f16x8 va = {};
    if (gm < M) {
      if constexpr (sizeof(AT) == 2) {
        va = *(const f16x8*)((const f16*)A + (size_t)gm * 128 + c8 * 8);
      } else {
        const float4* ap = (const float4*)((const float*)A + (size_t)gm * 128);
        float4 u0 = ap[c8 * 2], u1 = ap[c8 * 2 + 1];
        va[0] = (f16)u0.x; va[1] = (f16)u0.y; va[2] = (f16)u0.z; va[3] = (f16)u0.w;
        va[4] = (f16)u1.x; va[5] = (f16)u1.y; va[6] = (f16)u1.z; va[7] = (f16)u1.w;
      }
    }
    *(f16x8*)(As + row * 136 + c8 * 8) = va;
    *(f16x8*)(Bs + row * 136 + c8 * 8) = *(const f16x8*)(Bt + (size_t)(n0 + row) * 128 + c8 * 8);
  }
  __syncthreads();
  int wid = tid >> 6, lane = tid & 63;
  int wm = (wid & 1) * 64, wn = (wid >> 1) * 64;
  int lm = lane & 15, lk = lane >> 4;
  f32x4 acc[4][4] = {};
#pragma unroll
  for (int ks = 0; ks < 4; ks++) {
    int k0 = ks * 32;
    f16x8 a[4], b[4];
#pragma unroll
    for (int i = 0; i < 4; i++) {
      a[i] = *(const f16x8*)(As + (wm + i * 16 + lm) * 136 + k0 + lk * 8);
      b[i] = *(const f16x8*)(Bs + (wn + i * 16 + lm) * 136 + k0 + lk * 8);
    }
#pragma unroll
    for (int i = 0; i < 4; i++)
#pragma unroll
      for (int j = 0; j < 4; j++)
        acc[i][j] = __builtin_amdgcn_mfma_f32_16x16x32_f16(a[i], b[j], acc[i][j], 0, 0, 0);
  }
#pragma unroll
  for (int i = 0; i < 4; i++)
#pragma unroll
    for (int j = 0; j < 4; j++)
#pragma unroll
      for (int q = 0; q < 4; q++) {
        int gm = m0 + wm + i * 16 + lk * 4 + q;
        int gn = n0 + wn + j * 16 + lm;
        if (gm < M && gn < ncol) C[(size_t)gm * ncol + gn] = (f16)acc[i][j][q];
      }
}

// ---------------- edge aggregation for one column pass ----------------
// 256 threads = NB subgroups of PW lanes; subgroup g handles node blockIdx*NB+g.
template <int PW>
__global__ __launch_bounds__(256) void k_edge_ps(
    const f16* __restrict__ Y, const int* __restrict__ sps,
    const int* __restrict__ off, const float* __restrict__ bias,
    f16* __restrict__ hout, const int* __restrict__ mark, int N, int pass) {
  constexpr int NB = 256 / PW;
  __shared__ int c8[NB][8];
  __shared__ float sinv[NB][8];
  int t = threadIdx.x;
  int g = t / PW, st = t - g * PW;
  int n = blockIdx.x * NB + g;
  bool active = (n < N) && (!mark || mark[n] != 0);
  if (st < 8) c8[g][st] = 0;
  __syncthreads();
  int e0 = 0, e1 = 0;
  if (active) {
    e0 = off[n]; e1 = off[n + 1];
    for (int e = e0 + st; e < e1; e += PW)
      atomicAdd(&c8[g][((unsigned)sps[e]) >> 20], 1);
  }
  __syncthreads();
  if (st < 8) { int c = c8[g][st]; sinv[g][st] = 1.0f / (float)(c > 1 ? c : 1); }
  __syncthreads();
  if (!active) return;
  const int ldy = 9 * PW;
  float a = (float)Y[(size_t)n * ldy + 8 * PW + st] + bias[pass * PW + st];
  float a2 = 0.f;
  int e = e0;
  for (; e + 1 < e1; e += 2) {
    int p0 = sps[e], p1 = sps[e + 1];
    int s0 = p0 & 0xFFFFF, ty0 = ((unsigned)p0) >> 20;
    int s1 = p1 & 0xFFFFF, ty1 = ((unsigned)p1) >> 20;
    a  += (float)Y[(size_t)s0 * ldy + ty0 * PW + st] * sinv[g][ty0];
    a2 += (float)Y[(size_t)s1 * ldy + ty1 * PW + st] * sinv[g][ty1];
  }
  if (e < e1) {
    int p0 = sps[e];
    int s0 = p0 & 0xFFFFF, ty0 = ((unsigned)p0) >> 20;
    a += (float)Y[(size_t)s0 * ldy + ty0 * PW + st] * sinv[g][ty0];
  }
  a = fmaxf(a + a2, 0.f);
  hout[(size_t)n * 128 + pass * PW + st] = (f16)a;
}

// ---------------- layer 3: only at root rows, weights in LDS ----------------
__global__ __launch_bounds__(128) void k_layer3(const f16* __restrict__ h2,
                                                const int* __restrict__ sps,
                                                const int* __restrict__ off,
                                                const int* __restrict__ ridx,
                                                const float* __restrict__ wrel,
                                                const float* __restrict__ wroot,
                                                const float* __restrict__ b3,
                                                float* __restrict__ out) {
  __shared__ f16 W[9 * 2048];   // 0..7 = wrel3[r][k][c], 8 = root3[k][c]
  __shared__ float red[2][16];
  __shared__ int c8i[8];
  __shared__ float sinv_s[8];
  int t = threadIdx.x;
  int n = ridx[blockIdx.x];
  if (t < 8) c8i[t] = 0;
  for (int j = t; j < 9 * 2048; j += 128)
    W[j] = (f16)((j < 8 * 2048) ? wrel[j] : wroot[j - 8 * 2048]);
  __syncthreads();
  int e0 = off[n], e1 = off[n + 1];
  for (int e = e0 + t; e < e1; e += 128)
    atomicAdd(&c8i[((unsigned)sps[e]) >> 20], 1);
  __syncthreads();
  if (t < 8) { int c = c8i[t]; sinv_s[t] = 1.0f / (float)(c > 1 ? c : 1); }
  __syncthreads();
  int c = t & 15, kg = t >> 4;   // 8 k-groups of 16
  float a = 0.f;
  for (int e = e0; e < e1; e++) {
    int ps = sps[e];
    int s = ps & 0xFFFFF, ty = ((unsigned)ps) >> 20;
    float p = 0.f;
#pragma unroll
    for (int j = 0; j < 16; j++) {
      int k = kg * 16 + j;
      p += (float)h2[(size_t)s * 128 + k] * (float)W[ty * 2048 + k * 16 + c];
    }
    a += sinv_s[ty] * p;
  }
  {
    float p = 0.f;
#pragma unroll
    for (int j = 0; j < 16; j++) {
      int k = kg * 16 + j;
      p += (float)h2[(size_t)n * 128 + k] * (float)W[8 * 2048 + k * 16 + c];
    }
    a += p;
  }
  a += __shfl_xor(a, 16);
  a += __shfl_xor(a, 32);
  if ((t & 63) < 16) red[t >> 6][t & 15] = a;
  __syncthreads();
  if (t < 16) out[(size_t)blockIdx.x * 16 + t] = red[0][t] + red[1][t] + b3[t];
}

// ---------------- host ----------------
extern "C" void kernel_launch(void* const* d_in, const int* in_sizes, int n_in,
                              void* d_out, int out_size, void* d_ws, size_t ws_size,
                              hipStream_t stream) {
  const float* x     = (const float*)d_in[0];
  const int*   eidx  = (const int*)d_in[1];
  const int*   etyp  = (const int*)d_in[2];
  const int*   ridx  = (const int*)d_in[3];
  const float* wrel1 = (const float*)d_in[4];
  const float* root1 = (const float*)d_in[5];
  const float* b1    = (const float*)d_in[6];
  const float* wrel2 = (const float*)d_in[7];
  const float* root2 = (const float*)d_in[8];
  const float* b2    = (const float*)d_in[9];
  const float* wrel3 = (const float*)d_in[10];
  const float* root3 = (const float*)d_in[11];
  const float* b3    = (const float*)d_in[12];

  int N = in_sizes[0] / 128;
  int E = in_sizes[2];
  int NROOT = in_sizes[3];
  const int* esrc = eidx;
  const int* edst = eidx + E;

  char* p = (char*)d_ws;
  auto alloc = [&](size_t bytes) { void* r = (void*)p; p += (bytes + 255) & ~(size_t)255; return r; };
  int* off  = (int*)alloc((size_t)(N + 1) * 4);
  int* sps  = (int*)alloc((size_t)E * 4);
  f16* h1   = (f16*)alloc((size_t)N * 128 * 2);
  f16* h2   = (f16*)alloc((size_t)N * 128 * 2);
  int* mark = (int*)alloc((size_t)N * 4);
  f16* Wt   = (f16*)alloc((size_t)640 * 128 * 2);   // max 5 col-tiles

  size_t used = (size_t)(p - (char*)d_ws);
  size_t remain = ws_size > used ? ws_size - used : 0;
  int PW = (remain >= (size_t)N * 9 * 64 * 2 + (1u << 20)) ? 64 : 32;
  int ldy = 9 * PW;
  f16* Y = (f16*)alloc((size_t)N * ldy * 2);
  // fill/part live in Y's region (only used during setup, before any Y write)
  int* fill = (int*)Y;
  int* part = fill + N + 64;

  int eb = (E + 255) / 256;
  hipMemsetAsync(off, 0, (size_t)(N + 1) * 4, stream);
  hipMemsetAsync(fill, 0, (size_t)N * 4, stream);
  hipMemsetAsync(mark, 0, (size_t)N * 4, stream);
  k_hist<<<eb, 256, 0, stream>>>(edst, E, off);
  int nb1 = (N + 4095) / 4096;   // 25
  k_scan1<<<nb1, 256, 0, stream>>>(off, off, part, N);
  k_scan2<<<1, 256, 0, stream>>>(part, nb1);
  k_scan3<<<(N + 255) / 256, 256, 0, stream>>>(off, part, N);
  k_sentinel<<<1, 1, 0, stream>>>(off + N, E);
  k_scatter<<<eb, 256, 0, stream>>>(esrc, edst, etyp, E, off, fill, sps);
  k_mark<<<NROOT, 64, 0, stream>>>(ridx, off, sps, mark);

  int mb = (N + 127) / 128;
  int NT = (ldy + 127) / 128;        // 5 (PW=64) or 3 (PW=32)
  int npass = 128 / PW;
  int egrid64 = (N + 3) / 4, egrid32 = (N + 7) / 8;

  // layer 1: A = x (fp32)
  for (int ps = 0; ps < npass; ps++) {
    k_tpw<<<NT * 128, 128, 0, stream>>>(wrel1, root1, Wt, PW, ps);
    k_gemm<float><<<dim3(mb, NT), 256, 0, stream>>>(x, Wt, Y, N, ldy);
    if (PW == 64)
      k_edge_ps<64><<<egrid64, 256, 0, stream>>>(Y, sps, off, b1, h1, nullptr, N, ps);
    else
      k_edge_ps<32><<<egrid32, 256, 0, stream>>>(Y, sps, off, b1, h1, nullptr, N, ps);
  }
  // layer 2: A = h1 (f16), edge pass pruned to marked nodes
  for (int ps = 0; ps < npass; ps++) {
    k_tpw<<<NT * 128, 128, 0, stream>>>(wrel2, root2, Wt, PW, ps);
    k_gemm<f16><<<dim3(mb, NT), 256, 0, stream>>>(h1, Wt, Y, N, ldy);
    if (PW == 64)
      k_edge_ps<64><<<egrid64, 256, 0, stream>>>(Y, sps, off, b2, h2, mark, N, ps);
    else
      k_edge_ps<32><<<egrid32, 256, 0, stream>>>(Y, sps, off, b2, h2, mark, N, ps);
  }
  k_layer3<<<NROOT, 128, 0, stream>>>(h2, sps, off, ridx, wrel3, root3, b3,
                                      (float*)d_out);
}

// Round 6
// 637.477 us; speedup vs baseline: 4.7173x; 1.1758x over previous
//
#include <hip/hip_runtime.h>
#include <hip/hip_fp16.h>

// RGCN 3-layer, transform-first with column-split passes:
//   Y = A @ [W_0..W_7, W_root] restricted to output cols [p*PW,(p+1)*PW)
//   h[n, cols] = relu( Y[n,rootblk] + sum_e (1/cnt[n,ty]) * Y[src_e, ty-blk] + bias )
// Edges counting-sorted by dst (payload src|type<<20). Per-(node,type) inverse
// counts precomputed once (sinvp). Edge pass: 16-lane subgroups, f16x4 vector
// gather, shfl-based sinv broadcast. Layer-2 edge pass pruned to nodes layer-3
// reads. Layer 3 only at root rows. All matmuls fp16 MFMA.

typedef _Float16 f16;
typedef _Float16 f16x2 __attribute__((ext_vector_type(2)));
typedef _Float16 f16x4 __attribute__((ext_vector_type(4)));
typedef _Float16 f16x8 __attribute__((ext_vector_type(8)));
typedef float f32x4 __attribute__((ext_vector_type(4)));

#define NREL 8

// ---------------- setup kernels ----------------
__global__ void k_hist(const int* __restrict__ dst, int E, int* __restrict__ cnt) {
  int e = blockIdx.x * 256 + threadIdx.x;
  if (e < E) atomicAdd(&cnt[dst[e]], 1);
}

// exclusive scan pass 1 (in-place safe: each block reads then writes only its range)
__global__ void k_scan1(const int* __restrict__ in, int* __restrict__ out,
                        int* __restrict__ part, int n) {
  __shared__ int sh[256];
  int b = blockIdx.x, t = threadIdx.x;
  int base = b * 4096 + t * 16;
  int v[16]; int s = 0;
#pragma unroll
  for (int j = 0; j < 16; j++) { int idx = base + j; int x = (idx < n) ? in[idx] : 0; v[j] = s; s += x; }
  sh[t] = s; __syncthreads();
  for (int off = 1; off < 256; off <<= 1) {
    int x = 0; if (t >= off) x = sh[t - off];
    __syncthreads();
    if (t >= off) sh[t] += x;
    __syncthreads();
  }
  int excl = (t == 0) ? 0 : sh[t - 1];
  if (t == 255) part[b] = sh[255];
#pragma unroll
  for (int j = 0; j < 16; j++) { int idx = base + j; if (idx < n) out[idx] = v[j] + excl; }
}

__global__ void k_scan2(int* __restrict__ part, int nb) {  // nb <= 256, 1 block
  __shared__ int sh[256];
  int t = threadIdx.x;
  sh[t] = (t < nb) ? part[t] : 0; __syncthreads();
  for (int off = 1; off < 256; off <<= 1) {
    int x = 0; if (t >= off) x = sh[t - off];
    __syncthreads();
    if (t >= off) sh[t] += x;
    __syncthreads();
  }
  if (t < nb) part[t] = (t == 0) ? 0 : sh[t - 1];
}

__global__ void k_scan3(int* __restrict__ out, const int* __restrict__ part, int n) {
  int i = blockIdx.x * 256 + threadIdx.x;
  if (i < n) out[i] += part[i >> 12];
}

__global__ void k_sentinel(int* __restrict__ p, int v) { *p = v; }

__global__ void k_scatter(const int* __restrict__ src, const int* __restrict__ dstv,
                          const int* __restrict__ et, int E,
                          const int* __restrict__ off, int* __restrict__ fill,
                          int* __restrict__ sps) {
  int e = blockIdx.x * 256 + threadIdx.x;
  if (e >= E) return;
  int d = dstv[e];
  int pos = off[d] + atomicAdd(&fill[d], 1);
  sps[pos] = src[e] | (et[e] << 20);   // src < 2^20, type in bits 20..23
}

// mark nodes whose h2 is read by layer 3: roots + src of root in-edges
__global__ void k_mark(const int* __restrict__ ridx, const int* __restrict__ off,
                       const int* __restrict__ sps, int* __restrict__ mark) {
  int i = blockIdx.x, t = threadIdx.x;
  int n = ridx[i];
  if (t == 0) mark[n] = 1;
  int e0 = off[n], e1 = off[n + 1];
  for (int e = e0 + t; e < e1; e += 64) mark[sps[e] & 0xFFFFF] = 1;
}

// precompute per-(node,type) inverse counts: sinvp[n*8+ty] = 1/max(cnt,1)
__global__ __launch_bounds__(256) void k_sinvp(const int* __restrict__ sps,
                                               const int* __restrict__ off,
                                               float* __restrict__ sinvp, int N) {
  __shared__ int c[16][8];
  int t = threadIdx.x;
  int g = t >> 4, st = t & 15;
  int n = blockIdx.x * 16 + g;
  if (st < 8) c[g][st] = 0;
  __syncthreads();
  if (n < N) {
    int e0 = off[n], e1 = off[n + 1];
    for (int e = e0 + st; e < e1; e += 16)
      atomicAdd(&c[g][((unsigned)sps[e]) >> 20], 1);
  }
  __syncthreads();
  if (n < N && st < 8) {
    int cc = c[g][st];
    sinvp[n * 8 + st] = 1.0f / (float)(cc > 1 ? cc : 1);
  }
}

// weights for pass p: Wt[row][k], row = cb*PW + j -> source col p*PW+j of chunk cb
// (cb 0..7 = wrel[cb][k][col], cb 8 = wroot[k][col]); pad rows (>= 9*PW) zero.
__global__ void k_tpw(const float* __restrict__ wrel, const float* __restrict__ wroot,
                      f16* __restrict__ dst, int PW, int p) {
  int row = blockIdx.x, k = threadIdx.x;
  float v = 0.f;
  if (row < 9 * PW) {
    int cb = row / PW, j = row - cb * PW;
    int col = p * PW + j;
    v = (cb < 8) ? wrel[(size_t)cb * 16384 + k * 128 + col] : wroot[k * 128 + col];
  }
  dst[(size_t)row * 128 + k] = (f16)v;
}

// ---------------- GEMM: C[M x ncol] = A[M x 128] * Bt^T, Bt is [>=ncol][128] f16 ----
template <typename AT>
__global__ __launch_bounds__(256) void k_gemm(const AT* __restrict__ A,
                                              const f16* __restrict__ Bt,
                                              f16* __restrict__ C, int M, int ncol) {
  __shared__ f16 As[128 * 136];
  __shared__ f16 Bs[128 * 136];
  int m0 = blockIdx.x * 128, n0 = blockIdx.y * 128;
  int tid = threadIdx.x;
#pragma unroll
  for (int cch = 0; cch < 8; cch++) {
    int ci = tid + cch * 256;       // 0..2047, 8 elems each
    int row = ci >> 4, c8 = ci & 15;
    int gm = m0 + row;
    f16x8 va = {};
    if (gm < M) {
      if constexpr (sizeof(AT) == 2) {
        va = *(const f16x8*)((const f16*)A + (size_t)gm * 128 + c8 * 8);
      } else {
        const float4* ap = (const float4*)((const float*)A + (size_t)gm * 128);
        float4 u0 = ap[c8 * 2], u1 = ap[c8 * 2 + 1];
        va[0] = (f16)u0.x; va[1] = (f16)u0.y; va[2] = (f16)u0.z; va[3] = (f16)u0.w;
        va[4] = (f16)u1.x; va[5] = (f16)u1.y; va[6] = (f16)u1.z; va[7] = (f16)u1.w;
      }
    }
    *(f16x8*)(As + row * 136 + c8 * 8) = va;
    *(f16x8*)(Bs + row * 136 + c8 * 8) = *(const f16x8*)(Bt + (size_t)(n0 + row) * 128 + c8 * 8);
  }
  __syncthreads();
  int wid = tid >> 6, lane = tid & 63;
  int wm = (wid & 1) * 64, wn = (wid >> 1) * 64;
  int lm = lane & 15, lk = lane >> 4;
  f32x4 acc[4][4] = {};
#pragma unroll
  for (int ks = 0; ks < 4; ks++) {
    int k0 = ks * 32;
    f16x8 a[4], b[4];
#pragma unroll
    for (int i = 0; i < 4; i++) {
      a[i] = *(const f16x8*)(As + (wm + i * 16 + lm) * 136 + k0 + lk * 8);
      b[i] = *(const f16x8*)(Bs + (wn + i * 16 + lm) * 136 + k0 + lk * 8);
    }
#pragma unroll
    for (int i = 0; i < 4; i++)
#pragma unroll
      for (int j = 0; j < 4; j++)
        acc[i][j] = __builtin_amdgcn_mfma_f32_16x16x32_f16(a[i], b[j], acc[i][j], 0, 0, 0);
  }
#pragma unroll
  for (int i = 0; i < 4; i++)
#pragma unroll
    for (int j = 0; j < 4; j++)
#pragma unroll
      for (int q = 0; q < 4; q++) {
        int gm = m0 + wm + i * 16 + lk * 4 + q;
        int gn = n0 + wn + j * 16 + lm;
        if (gm < M && gn < ncol) C[(size_t)gm * ncol + gn] = (f16)acc[i][j][q];
      }
}

// ---------------- vectorized edge aggregation for one column pass ----------------
// 256 threads = 16 subgroups of 16 lanes; subgroup g handles node blockIdx*16+g.
// Each lane covers CPL = PW/16 consecutive cols via one f16x4/f16x2 load per edge.
template <int PW>
__global__ __launch_bounds__(256) void k_edge_v(
    const f16* __restrict__ Y, const int* __restrict__ sps,
    const int* __restrict__ off, const float* __restrict__ sinvp,
    const float* __restrict__ bias, f16* __restrict__ hout,
    const int* __restrict__ mark, int N, int pass) {
  constexpr int CPL = PW / 16;
  constexpr int LDY = 9 * PW;
  int t = threadIdx.x;
  int g = t >> 4, st = t & 15;
  int n = blockIdx.x * 16 + g;
  if (n >= N) return;
  if (mark && !mark[n]) return;
  float sv = (st < 8) ? sinvp[n * 8 + st] : 0.f;
  int e0 = off[n], e1 = off[n + 1];
  float a[CPL], b2[CPL];
  {
    const f16* rp = Y + (size_t)n * LDY + 8 * PW + st * CPL;
    const float* bp = bias + pass * PW + st * CPL;
#pragma unroll
    for (int q = 0; q < CPL; q++) { a[q] = (float)rp[q] + bp[q]; b2[q] = 0.f; }
  }
  int sgbase = t & 48;
  int e = e0;
  for (; e + 1 < e1; e += 2) {
    int p0 = sps[e], p1 = sps[e + 1];
    int s0 = p0 & 0xFFFFF, ty0 = ((unsigned)p0) >> 20;
    int s1 = p1 & 0xFFFFF, ty1 = ((unsigned)p1) >> 20;
    float sc0 = __shfl(sv, sgbase | ty0);
    float sc1 = __shfl(sv, sgbase | ty1);
    const f16* q0 = Y + (size_t)s0 * LDY + ty0 * PW + st * CPL;
    const f16* q1 = Y + (size_t)s1 * LDY + ty1 * PW + st * CPL;
    if constexpr (PW == 64) {
      f16x4 v0 = *(const f16x4*)q0;
      f16x4 v1 = *(const f16x4*)q1;
      a[0] += (float)v0[0] * sc0; a[1] += (float)v0[1] * sc0;
      a[2] += (float)v0[2] * sc0; a[3] += (float)v0[3] * sc0;
      b2[0] += (float)v1[0] * sc1; b2[1] += (float)v1[1] * sc1;
      b2[2] += (float)v1[2] * sc1; b2[3] += (float)v1[3] * sc1;
    } else {
      f16x2 v0 = *(const f16x2*)q0;
      f16x2 v1 = *(const f16x2*)q1;
      a[0] += (float)v0[0] * sc0; a[1] += (float)v0[1] * sc0;
      b2[0] += (float)v1[0] * sc1; b2[1] += (float)v1[1] * sc1;
    }
  }
  if (e < e1) {
    int p0 = sps[e];
    int s0 = p0 & 0xFFFFF, ty0 = ((unsigned)p0) >> 20;
    float sc0 = __shfl(sv, sgbase | ty0);
    const f16* q0 = Y + (size_t)s0 * LDY + ty0 * PW + st * CPL;
    if constexpr (PW == 64) {
      f16x4 v0 = *(const f16x4*)q0;
      a[0] += (float)v0[0] * sc0; a[1] += (float)v0[1] * sc0;
      a[2] += (float)v0[2] * sc0; a[3] += (float)v0[3] * sc0;
    } else {
      f16x2 v0 = *(const f16x2*)q0;
      a[0] += (float)v0[0] * sc0; a[1] += (float)v0[1] * sc0;
    }
  }
  if constexpr (PW == 64) {
    f16x4 o;
#pragma unroll
    for (int q = 0; q < 4; q++) o[q] = (f16)fmaxf(a[q] + b2[q], 0.f);
    *(f16x4*)(hout + (size_t)n * 128 + pass * PW + st * 4) = o;
  } else {
    f16x2 o;
#pragma unroll
    for (int q = 0; q < 2; q++) o[q] = (f16)fmaxf(a[q] + b2[q], 0.f);
    *(f16x2*)(hout + (size_t)n * 128 + pass * PW + st * 2) = o;
  }
}

// ---------------- layer 3: only at root rows, weights in LDS ----------------
__global__ __launch_bounds__(128) void k_layer3(const f16* __restrict__ h2,
                                                const int* __restrict__ sps,
                                                const int* __restrict__ off,
                                                const float* __restrict__ sinvp,
                                                const int* __restrict__ ridx,
                                                const float* __restrict__ wrel,
                                                const float* __restrict__ wroot,
                                                const float* __restrict__ b3,
                                                float* __restrict__ out) {
  __shared__ f16 W[9 * 2048];   // 0..7 = wrel3[r][k][c], 8 = root3[k][c]
  __shared__ float red[2][16];
  __shared__ float sinv_s[8];
  int t = threadIdx.x;
  int n = ridx[blockIdx.x];
  for (int j = t; j < 9 * 2048; j += 128)
    W[j] = (f16)((j < 8 * 2048) ? wrel[j] : wroot[j - 8 * 2048]);
  if (t < 8) sinv_s[t] = sinvp[n * 8 + t];
  __syncthreads();
  int e0 = off[n], e1 = off[n + 1];
  int c = t & 15, kg = t >> 4;   // 8 k-groups of 16
  float a = 0.f;
  for (int e = e0; e < e1; e++) {
    int ps = sps[e];
    int s = ps & 0xFFFFF, ty = ((unsigned)ps) >> 20;
    float p = 0.f;
#pragma unroll
    for (int j = 0; j < 16; j++) {
      int k = kg * 16 + j;
      p += (float)h2[(size_t)s * 128 + k] * (float)W[ty * 2048 + k * 16 + c];
    }
    a += sinv_s[ty] * p;
  }
  {
    float p = 0.f;
#pragma unroll
    for (int j = 0; j < 16; j++) {
      int k = kg * 16 + j;
      p += (float)h2[(size_t)n * 128 + k] * (float)W[8 * 2048 + k * 16 + c];
    }
    a += p;
  }
  a += __shfl_xor(a, 16);
  a += __shfl_xor(a, 32);
  if ((t & 63) < 16) red[t >> 6][t & 15] = a;
  __syncthreads();
  if (t < 16) out[(size_t)blockIdx.x * 16 + t] = red[0][t] + red[1][t] + b3[t];
}

// ---------------- host ----------------
extern "C" void kernel_launch(void* const* d_in, const int* in_sizes, int n_in,
                              void* d_out, int out_size, void* d_ws, size_t ws_size,
                              hipStream_t stream) {
  const float* x     = (const float*)d_in[0];
  const int*   eidx  = (const int*)d_in[1];
  const int*   etyp  = (const int*)d_in[2];
  const int*   ridx  = (const int*)d_in[3];
  const float* wrel1 = (const float*)d_in[4];
  const float* root1 = (const float*)d_in[5];
  const float* b1    = (const float*)d_in[6];
  const float* wrel2 = (const float*)d_in[7];
  const float* root2 = (const float*)d_in[8];
  const float* b2    = (const float*)d_in[9];
  const float* wrel3 = (const float*)d_in[10];
  const float* root3 = (const float*)d_in[11];
  const float* b3    = (const float*)d_in[12];

  int N = in_sizes[0] / 128;
  int E = in_sizes[2];
  int NROOT = in_sizes[3];
  const int* esrc = eidx;
  const int* edst = eidx + E;

  char* p = (char*)d_ws;
  auto alloc = [&](size_t bytes) { void* r = (void*)p; p += (bytes + 255) & ~(size_t)255; return r; };
  int*   off   = (int*)alloc((size_t)(N + 1) * 4);
  int*   sps   = (int*)alloc((size_t)E * 4);
  f16*   h1    = (f16*)alloc((size_t)N * 128 * 2);
  f16*   h2    = (f16*)alloc((size_t)N * 128 * 2);
  int*   mark  = (int*)alloc((size_t)N * 4);
  float* sinvp = (float*)alloc((size_t)N * 8 * 4);
  f16*   Wt    = (f16*)alloc((size_t)640 * 128 * 2);   // max 5 col-tiles

  size_t used = (size_t)(p - (char*)d_ws);
  size_t remain = ws_size > used ? ws_size - used : 0;
  int PW = (remain >= (size_t)N * 9 * 64 * 2 + (1u << 20)) ? 64 : 32;
  int ldy = 9 * PW;
  f16* Y = (f16*)alloc((size_t)N * ldy * 2);
  // fill/part live in Y's region (only used during setup, before any Y write)
  int* fill = (int*)Y;
  int* part = fill + N + 64;

  int eb = (E + 255) / 256;
  hipMemsetAsync(off, 0, (size_t)(N + 1) * 4, stream);
  hipMemsetAsync(fill, 0, (size_t)N * 4, stream);
  hipMemsetAsync(mark, 0, (size_t)N * 4, stream);
  k_hist<<<eb, 256, 0, stream>>>(edst, E, off);
  int nb1 = (N + 4095) / 4096;   // 25
  k_scan1<<<nb1, 256, 0, stream>>>(off, off, part, N);
  k_scan2<<<1, 256, 0, stream>>>(part, nb1);
  k_scan3<<<(N + 255) / 256, 256, 0, stream>>>(off, part, N);
  k_sentinel<<<1, 1, 0, stream>>>(off + N, E);
  k_scatter<<<eb, 256, 0, stream>>>(esrc, edst, etyp, E, off, fill, sps);
  k_mark<<<NROOT, 64, 0, stream>>>(ridx, off, sps, mark);
  int ng16 = (N + 15) / 16;
  k_sinvp<<<ng16, 256, 0, stream>>>(sps, off, sinvp, N);

  int mb = (N + 127) / 128;
  int NT = (ldy + 127) / 128;        // 5 (PW=64) or 3 (PW=32)
  int npass = 128 / PW;

  // layer 1: A = x (fp32)
  for (int ps = 0; ps < npass; ps++) {
    k_tpw<<<NT * 128, 128, 0, stream>>>(wrel1, root1, Wt, PW, ps);
    k_gemm<float><<<dim3(mb, NT), 256, 0, stream>>>(x, Wt, Y, N, ldy);
    if (PW == 64)
      k_edge_v<64><<<ng16, 256, 0, stream>>>(Y, sps, off, sinvp, b1, h1, nullptr, N, ps);
    else
      k_edge_v<32><<<ng16, 256, 0, stream>>>(Y, sps, off, sinvp, b1, h1, nullptr, N, ps);
  }
  // layer 2: A = h1 (f16), edge pass pruned to marked nodes
  for (int ps = 0; ps < npass; ps++) {
    k_tpw<<<NT * 128, 128, 0, stream>>>(wrel2, root2, Wt, PW, ps);
    k_gemm<f16><<<dim3(mb, NT), 256, 0, stream>>>(h1, Wt, Y, N, ldy);
    if (PW == 64)
      k_edge_v<64><<<ng16, 256, 0, stream>>>(Y, sps, off, sinvp, b2, h2, mark, N, ps);
    else
      k_edge_v<32><<<ng16, 256, 0, stream>>>(Y, sps, off, sinvp, b2, h2, mark, N, ps);
  }
  k_layer3<<<NROOT, 128, 0, stream>>>(h2, sps, off, sinvp, ridx, wrel3, root3, b3,
                                      (float*)d_out);
}

// Round 7
// 575.522 us; speedup vs baseline: 5.2251x; 1.1076x over previous
//
#include <hip/hip_runtime.h>
#include <hip/hip_fp16.h>

// RGCN 3-layer, transform-first with column-split passes:
//   Y = A @ [W_0..W_7, W_root] restricted to output cols [p*PW,(p+1)*PW)
//   h[n, cols] = relu( Y[n,rootblk] + sum_e (1/cnt[n,ty]) * Y[src_e, ty-blk] + bias )
// Edges counting-sorted by dst via TWO-PHASE bucketed scatter (kills 64B
// write-allocate thrash of the naive scatter). Per-(node,type) inverse counts
// precomputed once (sinvp). Edge pass: 16-lane subgroups, f16x4 vector gather,
// shfl-based sinv broadcast. Layer-2 edge pass pruned to nodes layer-3 reads.
// Layer 3 only at root rows. All matmuls fp16 MFMA.

typedef _Float16 f16;
typedef _Float16 f16x2 __attribute__((ext_vector_type(2)));
typedef _Float16 f16x4 __attribute__((ext_vector_type(4)));
typedef _Float16 f16x8 __attribute__((ext_vector_type(8)));
typedef float f32x4 __attribute__((ext_vector_type(4)));

#define NREL 8
#define ACHUNK 8192

// ---------------- setup kernels ----------------
__global__ void k_hist(const int* __restrict__ dst, int E, int* __restrict__ cnt) {
  int e = blockIdx.x * 256 + threadIdx.x;
  if (e < E) atomicAdd(&cnt[dst[e]], 1);
}

// exclusive scan pass 1 (in-place safe: each block reads then writes only its range)
__global__ void k_scan1(const int* __restrict__ in, int* __restrict__ out,
                        int* __restrict__ part, int n) {
  __shared__ int sh[256];
  int b = blockIdx.x, t = threadIdx.x;
  int base = b * 4096 + t * 16;
  int v[16]; int s = 0;
#pragma unroll
  for (int j = 0; j < 16; j++) { int idx = base + j; int x = (idx < n) ? in[idx] : 0; v[j] = s; s += x; }
  sh[t] = s; __syncthreads();
  for (int off = 1; off < 256; off <<= 1) {
    int x = 0; if (t >= off) x = sh[t - off];
    __syncthreads();
    if (t >= off) sh[t] += x;
    __syncthreads();
  }
  int excl = (t == 0) ? 0 : sh[t - 1];
  if (t == 255) part[b] = sh[255];
#pragma unroll
  for (int j = 0; j < 16; j++) { int idx = base + j; if (idx < n) out[idx] = v[j] + excl; }
}

__global__ void k_scan2(int* __restrict__ part, int nb) {  // nb <= 256, 1 block
  __shared__ int sh[256];
  int t = threadIdx.x;
  sh[t] = (t < nb) ? part[t] : 0; __syncthreads();
  for (int off = 1; off < 256; off <<= 1) {
    int x = 0; if (t >= off) x = sh[t - off];
    __syncthreads();
    if (t >= off) sh[t] += x;
    __syncthreads();
  }
  if (t < nb) part[t] = (t == 0) ? 0 : sh[t - 1];
}

__global__ void k_scan3(int* __restrict__ out, const int* __restrict__ part, int n) {
  int i = blockIdx.x * 256 + threadIdx.x;
  if (i < n) out[i] += part[i >> 12];
}

__global__ void k_sentinel(int* __restrict__ p, int v) { *p = v; }

// ---- two-phase bucketed scatter (bucket = 256 consecutive dst nodes) ----
// Phase A: chunk of edges -> bucket-grouped tmp (payload src|ty<<20|dstlocal<<23)
__global__ __launch_bounds__(256) void k_bucketA(
    const int* __restrict__ src, const int* __restrict__ dstv,
    const int* __restrict__ et, int E, const int* __restrict__ off,
    int* __restrict__ bfill, int* __restrict__ tmp, int nbuck) {
  __shared__ int hist[512];
  __shared__ int base[512];
  int t = threadIdx.x;
  int lo = blockIdx.x * ACHUNK;
  int hi = lo + ACHUNK < E ? lo + ACHUNK : E;
  for (int i = t; i < nbuck; i += 256) hist[i] = 0;
  __syncthreads();
  for (int e = lo + t; e < hi; e += 256)
    atomicAdd(&hist[dstv[e] >> 8], 1);
  __syncthreads();
  for (int i = t; i < nbuck; i += 256) {
    int c = hist[i];
    base[i] = c ? (off[i << 8] + atomicAdd(&bfill[i], c)) : 0;
  }
  __syncthreads();
  for (int e = lo + t; e < hi; e += 256) {
    int d = dstv[e];
    int b = d >> 8;
    int pos = atomicAdd(&base[b], 1);
    tmp[pos] = src[e] | (et[e] << 20) | ((d & 255) << 23);
  }
}

// Phase B: per-bucket exact scatter into the bucket's contiguous sps window
__global__ __launch_bounds__(256) void k_bucketB(const int* __restrict__ tmp,
                                                 const int* __restrict__ off,
                                                 int* __restrict__ sps, int N) {
  __shared__ int offs[257];
  __shared__ int fill[256];
  int b = blockIdx.x, t = threadIdx.x;
  int n0 = b << 8;
  int nn = (N - n0) < 256 ? (N - n0) : 256;
  if (t < nn) { offs[t] = off[n0 + t]; fill[t] = 0; }
  if (t == 0) offs[nn] = off[n0 + nn];
  __syncthreads();
  int e0 = offs[0], e1 = offs[nn];
  for (int e = e0 + t; e < e1; e += 256) {
    int v = tmp[e];
    int dl = (v >> 23) & 255;
    int pos = offs[dl] + atomicAdd(&fill[dl], 1);
    sps[pos] = v & 0x7FFFFF;
  }
}

// fallback direct scatter (N > 131072)
__global__ void k_scatter(const int* __restrict__ src, const int* __restrict__ dstv,
                          const int* __restrict__ et, int E,
                          const int* __restrict__ off, int* __restrict__ fill,
                          int* __restrict__ sps) {
  int e = blockIdx.x * 256 + threadIdx.x;
  if (e >= E) return;
  int d = dstv[e];
  int pos = off[d] + atomicAdd(&fill[d], 1);
  sps[pos] = src[e] | (et[e] << 20);
}

// mark nodes whose h2 is read by layer 3: roots + src of root in-edges
__global__ void k_mark(const int* __restrict__ ridx, const int* __restrict__ off,
                       const int* __restrict__ sps, int* __restrict__ mark) {
  int i = blockIdx.x, t = threadIdx.x;
  int n = ridx[i];
  if (t == 0) mark[n] = 1;
  int e0 = off[n], e1 = off[n + 1];
  for (int e = e0 + t; e < e1; e += 64) mark[sps[e] & 0xFFFFF] = 1;
}

// precompute per-(node,type) inverse counts: sinvp[n*8+ty] = 1/max(cnt,1)
__global__ __launch_bounds__(256) void k_sinvp(const int* __restrict__ sps,
                                               const int* __restrict__ off,
                                               float* __restrict__ sinvp, int N) {
  __shared__ int c[16][8];
  int t = threadIdx.x;
  int g = t >> 4, st = t & 15;
  int n = blockIdx.x * 16 + g;
  if (st < 8) c[g][st] = 0;
  __syncthreads();
  if (n < N) {
    int e0 = off[n], e1 = off[n + 1];
    for (int e = e0 + st; e < e1; e += 16)
      atomicAdd(&c[g][((unsigned)sps[e]) >> 20], 1);
  }
  __syncthreads();
  if (n < N && st < 8) {
    int cc = c[g][st];
    sinvp[n * 8 + st] = 1.0f / (float)(cc > 1 ? cc : 1);
  }
}

// weights for pass p: Wt[row][k], row = cb*PW + j -> source col p*PW+j of chunk cb
// (cb 0..7 = wrel[cb][k][col], cb 8 = wroot[k][col]); pad rows (>= 9*PW) zero.
__global__ void k_tpw(const float* __restrict__ wrel, const float* __restrict__ wroot,
                      f16* __restrict__ dst, int PW, int p) {
  int row = blockIdx.x, k = threadIdx.x;
  float v = 0.f;
  if (row < 9 * PW) {
    int cb = row / PW, j = row - cb * PW;
    int col = p * PW + j;
    v = (cb < 8) ? wrel[(size_t)cb * 16384 + k * 128 + col] : wroot[k * 128 + col];
  }
  dst[(size_t)row * 128 + k] = (f16)v;
}

// ---------------- GEMM: C[M x ncol] = A[M x 128] * Bt^T, Bt is [>=ncol][128] f16 ----
template <typename AT>
__global__ __launch_bounds__(256) void k_gemm(const AT* __restrict__ A,
                                              const f16* __restrict__ Bt,
                                              f16* __restrict__ C, int M, int ncol) {
  __shared__ f16 As[128 * 136];
  __shared__ f16 Bs[128 * 136];
  int m0 = blockIdx.x * 128, n0 = blockIdx.y * 128;
  int tid = threadIdx.x;
#pragma unroll
  for (int cch = 0; cch < 8; cch++) {
    int ci = tid + cch * 256;       // 0..2047, 8 elems each
    int row = ci >> 4, c8 = ci & 15;
    int gm = m0 + row;
    f16x8 va = {};
    if (gm < M) {
      if constexpr (sizeof(AT) == 2) {
        va = *(const f16x8*)((const f16*)A + (size_t)gm * 128 + c8 * 8);
      } else {
        const float4* ap = (const float4*)((const float*)A + (size_t)gm * 128);
        float4 u0 = ap[c8 * 2], u1 = ap[c8 * 2 + 1];
        va[0] = (f16)u0.x; va[1] = (f16)u0.y; va[2] = (f16)u0.z; va[3] = (f16)u0.w;
        va[4] = (f16)u1.x; va[5] = (f16)u1.y; va[6] = (f16)u1.z; va[7] = (f16)u1.w;
      }
    }
    *(f16x8*)(As + row * 136 + c8 * 8) = va;
    *(f16x8*)(Bs + row * 136 + c8 * 8) = *(const f16x8*)(Bt + (size_t)(n0 + row) * 128 + c8 * 8);
  }
  __syncthreads();
  int wid = tid >> 6, lane = tid & 63;
  int wm = (wid & 1) * 64, wn = (wid >> 1) * 64;
  int lm = lane & 15, lk = lane >> 4;
  f32x4 acc[4][4] = {};
#pragma unroll
  for (int ks = 0; ks < 4; ks++) {
    int k0 = ks * 32;
    f16x8 a[4], b[4];
#pragma unroll
    for (int i = 0; i < 4; i++) {
      a[i] = *(const f16x8*)(As + (wm + i * 16 + lm) * 136 + k0 + lk * 8);
      b[i] = *(const f16x8*)(Bs + (wn + i * 16 + lm) * 136 + k0 + lk * 8);
    }
#pragma unroll
    for (int i = 0; i < 4; i++)
#pragma unroll
      for (int j = 0; j < 4; j++)
        acc[i][j] = __builtin_amdgcn_mfma_f32_16x16x32_f16(a[i], b[j], acc[i][j], 0, 0, 0);
  }
#pragma unroll
  for (int i = 0; i < 4; i++)
#pragma unroll
    for (int j = 0; j < 4; j++)
#pragma unroll
      for (int q = 0; q < 4; q++) {
        int gm = m0 + wm + i * 16 + lk * 4 + q;
        int gn = n0 + wn + j * 16 + lm;
        if (gm < M && gn < ncol) C[(size_t)gm * ncol + gn] = (f16)acc[i][j][q];
      }
}

// ---------------- vectorized edge aggregation for one column pass ----------------
// 256 threads = 16 subgroups of 16 lanes; subgroup g handles node blockIdx*16+g.
// Each lane covers CPL = PW/16 consecutive cols via one f16x4/f16x2 load per edge.
template <int PW>
__global__ __launch_bounds__(256) void k_edge_v(
    const f16* __restrict__ Y, const int* __restrict__ sps,
    const int* __restrict__ off, const float* __restrict__ sinvp,
    const float* __restrict__ bias, f16* __restrict__ hout,
    const int* __restrict__ mark, int N, int pass) {
  constexpr int CPL = PW / 16;
  constexpr int LDY = 9 * PW;
  int t = threadIdx.x;
  int g = t >> 4, st = t & 15;
  int n = blockIdx.x * 16 + g;
  if (n >= N) return;
  if (mark && !mark[n]) return;
  float sv = (st < 8) ? sinvp[n * 8 + st] : 0.f;
  int e0 = off[n], e1 = off[n + 1];
  float a[CPL], b2[CPL];
  {
    const f16* rp = Y + (size_t)n * LDY + 8 * PW + st * CPL;
    const float* bp = bias + pass * PW + st * CPL;
#pragma unroll
    for (int q = 0; q < CPL; q++) { a[q] = (float)rp[q] + bp[q]; b2[q] = 0.f; }
  }
  int sgbase = t & 48;
  int e = e0;
  for (; e + 1 < e1; e += 2) {
    int p0 = sps[e], p1 = sps[e + 1];
    int s0 = p0 & 0xFFFFF, ty0 = ((unsigned)p0) >> 20;
    int s1 = p1 & 0xFFFFF, ty1 = ((unsigned)p1) >> 20;
    float sc0 = __shfl(sv, sgbase | ty0);
    float sc1 = __shfl(sv, sgbase | ty1);
    const f16* q0 = Y + (size_t)s0 * LDY + ty0 * PW + st * CPL;
    const f16* q1 = Y + (size_t)s1 * LDY + ty1 * PW + st * CPL;
    if constexpr (PW == 64) {
      f16x4 v0 = *(const f16x4*)q0;
      f16x4 v1 = *(const f16x4*)q1;
      a[0] += (float)v0[0] * sc0; a[1] += (float)v0[1] * sc0;
      a[2] += (float)v0[2] * sc0; a[3] += (float)v0[3] * sc0;
      b2[0] += (float)v1[0] * sc1; b2[1] += (float)v1[1] * sc1;
      b2[2] += (float)v1[2] * sc1; b2[3] += (float)v1[3] * sc1;
    } else {
      f16x2 v0 = *(const f16x2*)q0;
      f16x2 v1 = *(const f16x2*)q1;
      a[0] += (float)v0[0] * sc0; a[1] += (float)v0[1] * sc0;
      b2[0] += (float)v1[0] * sc1; b2[1] += (float)v1[1] * sc1;
    }
  }
  if (e < e1) {
    int p0 = sps[e];
    int s0 = p0 & 0xFFFFF, ty0 = ((unsigned)p0) >> 20;
    float sc0 = __shfl(sv, sgbase | ty0);
    const f16* q0 = Y + (size_t)s0 * LDY + ty0 * PW + st * CPL;
    if constexpr (PW == 64) {
      f16x4 v0 = *(const f16x4*)q0;
      a[0] += (float)v0[0] * sc0; a[1] += (float)v0[1] * sc0;
      a[2] += (float)v0[2] * sc0; a[3] += (float)v0[3] * sc0;
    } else {
      f16x2 v0 = *(const f16x2*)q0;
      a[0] += (float)v0[0] * sc0; a[1] += (float)v0[1] * sc0;
    }
  }
  if constexpr (PW == 64) {
    f16x4 o;
#pragma unroll
    for (int q = 0; q < 4; q++) o[q] = (f16)fmaxf(a[q] + b2[q], 0.f);
    *(f16x4*)(hout + (size_t)n * 128 + pass * PW + st * 4) = o;
  } else {
    f16x2 o;
#pragma unroll
    for (int q = 0; q < 2; q++) o[q] = (f16)fmaxf(a[q] + b2[q], 0.f);
    *(f16x2*)(hout + (size_t)n * 128 + pass * PW + st * 2) = o;
  }
}

// ---------------- layer 3: only at root rows, weights in LDS ----------------
__global__ __launch_bounds__(128) void k_layer3(const f16* __restrict__ h2,
                                                const int* __restrict__ sps,
                                                const int* __restrict__ off,
                                                const float* __restrict__ sinvp,
                                                const int* __restrict__ ridx,
                                                const float* __restrict__ wrel,
                                                const float* __restrict__ wroot,
                                                const float* __restrict__ b3,
                                                float* __restrict__ out) {
  __shared__ f16 W[9 * 2048];   // 0..7 = wrel3[r][k][c], 8 = root3[k][c]
  __shared__ float red[2][16];
  __shared__ float sinv_s[8];
  int t = threadIdx.x;
  int n = ridx[blockIdx.x];
  for (int j = t; j < 9 * 2048; j += 128)
    W[j] = (f16)((j < 8 * 2048) ? wrel[j] : wroot[j - 8 * 2048]);
  if (t < 8) sinv_s[t] = sinvp[n * 8 + t];
  __syncthreads();
  int e0 = off[n], e1 = off[n + 1];
  int c = t & 15, kg = t >> 4;   // 8 k-groups of 16
  float a = 0.f;
  for (int e = e0; e < e1; e++) {
    int ps = sps[e];
    int s = ps & 0xFFFFF, ty = ((unsigned)ps) >> 20;
    float p = 0.f;
#pragma unroll
    for (int j = 0; j < 16; j++) {
      int k = kg * 16 + j;
      p += (float)h2[(size_t)s * 128 + k] * (float)W[ty * 2048 + k * 16 + c];
    }
    a += sinv_s[ty] * p;
  }
  {
    float p = 0.f;
#pragma unroll
    for (int j = 0; j < 16; j++) {
      int k = kg * 16 + j;
      p += (float)h2[(size_t)n * 128 + k] * (float)W[8 * 2048 + k * 16 + c];
    }
    a += p;
  }
  a += __shfl_xor(a, 16);
  a += __shfl_xor(a, 32);
  if ((t & 63) < 16) red[t >> 6][t & 15] = a;
  __syncthreads();
  if (t < 16) out[(size_t)blockIdx.x * 16 + t] = red[0][t] + red[1][t] + b3[t];
}

// ---------------- host ----------------
extern "C" void kernel_launch(void* const* d_in, const int* in_sizes, int n_in,
                              void* d_out, int out_size, void* d_ws, size_t ws_size,
                              hipStream_t stream) {
  const float* x     = (const float*)d_in[0];
  const int*   eidx  = (const int*)d_in[1];
  const int*   etyp  = (const int*)d_in[2];
  const int*   ridx  = (const int*)d_in[3];
  const float* wrel1 = (const float*)d_in[4];
  const float* root1 = (const float*)d_in[5];
  const float* b1    = (const float*)d_in[6];
  const float* wrel2 = (const float*)d_in[7];
  const float* root2 = (const float*)d_in[8];
  const float* b2    = (const float*)d_in[9];
  const float* wrel3 = (const float*)d_in[10];
  const float* root3 = (const float*)d_in[11];
  const float* b3    = (const float*)d_in[12];

  int N = in_sizes[0] / 128;
  int E = in_sizes[2];
  int NROOT = in_sizes[3];
  const int* esrc = eidx;
  const int* edst = eidx + E;

  char* p = (char*)d_ws;
  auto alloc = [&](size_t bytes) { void* r = (void*)p; p += (bytes + 255) & ~(size_t)255; return r; };
  int*   off   = (int*)alloc((size_t)(N + 1) * 4);
  int*   sps   = (int*)alloc((size_t)E * 4);
  f16*   h1    = (f16*)alloc((size_t)N * 128 * 2);
  f16*   h2    = (f16*)alloc((size_t)N * 128 * 2);
  int*   mark  = (int*)alloc((size_t)N * 4);
  float* sinvp = (float*)alloc((size_t)N * 8 * 4);
  f16*   Wt    = (f16*)alloc((size_t)640 * 128 * 2);   // max 5 col-tiles

  size_t used = (size_t)(p - (char*)d_ws);
  size_t remain = ws_size > used ? ws_size - used : 0;
  int PW = (remain >= (size_t)N * 9 * 64 * 2 + (1u << 20)) ? 64 : 32;
  int ldy = 9 * PW;
  f16* Y = (f16*)alloc((size_t)N * ldy * 2);
  // setup-only scratch lives in Y's region (dead until first GEMM writes Y):
  int* tmp   = (int*)Y;            // E ints (phase-A bucket-grouped edges)
  int* bfill = tmp + E;            // 512 ints
  int* part  = bfill + 512;        // 4096 ints (scan partials)
  int* fill  = part + 4096;        // N ints (fallback scatter only)

  int eb = (E + 255) / 256;
  hipMemsetAsync(off, 0, (size_t)(N + 1) * 4, stream);
  hipMemsetAsync(bfill, 0, 512 * 4, stream);
  hipMemsetAsync(mark, 0, (size_t)N * 4, stream);
  k_hist<<<eb, 256, 0, stream>>>(edst, E, off);
  int nb1 = (N + 4095) / 4096;   // 25
  k_scan1<<<nb1, 256, 0, stream>>>(off, off, part, N);
  k_scan2<<<1, 256, 0, stream>>>(part, nb1);
  k_scan3<<<(N + 255) / 256, 256, 0, stream>>>(off, part, N);
  k_sentinel<<<1, 1, 0, stream>>>(off + N, E);

  int nbuck = (N + 255) >> 8;
  if (nbuck <= 512) {
    int nbA = (E + ACHUNK - 1) / ACHUNK;
    k_bucketA<<<nbA, 256, 0, stream>>>(esrc, edst, etyp, E, off, bfill, tmp, nbuck);
    k_bucketB<<<nbuck, 256, 0, stream>>>(tmp, off, sps, N);
  } else {
    hipMemsetAsync(fill, 0, (size_t)N * 4, stream);
    k_scatter<<<eb, 256, 0, stream>>>(esrc, edst, etyp, E, off, fill, sps);
  }
  k_mark<<<NROOT, 64, 0, stream>>>(ridx, off, sps, mark);
  int ng16 = (N + 15) / 16;
  k_sinvp<<<ng16, 256, 0, stream>>>(sps, off, sinvp, N);

  int mb = (N + 127) / 128;
  int NT = (ldy + 127) / 128;        // 5 (PW=64) or 3 (PW=32)
  int npass = 128 / PW;

  // layer 1: A = x (fp32)
  for (int ps = 0; ps < npass; ps++) {
    k_tpw<<<NT * 128, 128, 0, stream>>>(wrel1, root1, Wt, PW, ps);
    k_gemm<float><<<dim3(mb, NT), 256, 0, stream>>>(x, Wt, Y, N, ldy);
    if (PW == 64)
      k_edge_v<64><<<ng16, 256, 0, stream>>>(Y, sps, off, sinvp, b1, h1, nullptr, N, ps);
    else
      k_edge_v<32><<<ng16, 256, 0, stream>>>(Y, sps, off, sinvp, b1, h1, nullptr, N, ps);
  }
  // layer 2: A = h1 (f16), edge pass pruned to marked nodes
  for (int ps = 0; ps < npass; ps++) {
    k_tpw<<<NT * 128, 128, 0, stream>>>(wrel2, root2, Wt, PW, ps);
    k_gemm<f16><<<dim3(mb, NT), 256, 0, stream>>>(h1, Wt, Y, N, ldy);
    if (PW == 64)
      k_edge_v<64><<<ng16, 256, 0, stream>>>(Y, sps, off, sinvp, b2, h2, mark, N, ps);
    else
      k_edge_v<32><<<ng16, 256, 0, stream>>>(Y, sps, off, sinvp, b2, h2, mark, N, ps);
  }
  k_layer3<<<NROOT, 128, 0, stream>>>(h2, sps, off, sinvp, ridx, wrel3, root3, b3,
                                      (float*)d_out);
}

// Round 8
// 549.559 us; speedup vs baseline: 5.4720x; 1.0472x over previous
//
#include <hip/hip_runtime.h>
#include <hip/hip_fp16.h>

// RGCN 3-layer, transform-first with column-split passes:
//   Y = A @ [W_0..W_7, W_root] restricted to output cols [p*PW,(p+1)*PW)
//   h[n, cols] = relu( Y[n,rootblk] + sum_e (1/cnt[n,ty]) * Y[src_e, ty-blk] + bias )
// Edges counting-sorted by dst via two-phase bucketed scatter. sinvp precomputed.
// Edge pass: 16-lane subgroups, f16x4 vector gather, shfl sinv broadcast.
// GEMM: A-only LDS staging (B read from L2-resident Wt), f16x8 repack epilogue,
// grid ordered for A-tile L2 reuse. x pre-converted to f16 (into h2; safe alias:
// layer3 reads only marked rows, which layer-2 edge pass overwrites).

typedef _Float16 f16;
typedef _Float16 f16x2 __attribute__((ext_vector_type(2)));
typedef _Float16 f16x4 __attribute__((ext_vector_type(4)));
typedef _Float16 f16x8 __attribute__((ext_vector_type(8)));
typedef float f32x4 __attribute__((ext_vector_type(4)));

#define NREL 8
#define ACHUNK 8192

// ---------------- setup kernels ----------------
__global__ void k_hist(const int* __restrict__ dst, int E, int* __restrict__ cnt) {
  int e = blockIdx.x * 256 + threadIdx.x;
  if (e < E) atomicAdd(&cnt[dst[e]], 1);
}

// exclusive scan pass 1 (in-place safe: each block reads then writes only its range)
__global__ void k_scan1(const int* __restrict__ in, int* __restrict__ out,
                        int* __restrict__ part, int n) {
  __shared__ int sh[256];
  int b = blockIdx.x, t = threadIdx.x;
  int base = b * 4096 + t * 16;
  int v[16]; int s = 0;
#pragma unroll
  for (int j = 0; j < 16; j++) { int idx = base + j; int x = (idx < n) ? in[idx] : 0; v[j] = s; s += x; }
  sh[t] = s; __syncthreads();
  for (int off = 1; off < 256; off <<= 1) {
    int x = 0; if (t >= off) x = sh[t - off];
    __syncthreads();
    if (t >= off) sh[t] += x;
    __syncthreads();
  }
  int excl = (t == 0) ? 0 : sh[t - 1];
  if (t == 255) part[b] = sh[255];
#pragma unroll
  for (int j = 0; j < 16; j++) { int idx = base + j; if (idx < n) out[idx] = v[j] + excl; }
}

__global__ void k_scan2(int* __restrict__ part, int nb) {  // nb <= 256, 1 block
  __shared__ int sh[256];
  int t = threadIdx.x;
  sh[t] = (t < nb) ? part[t] : 0; __syncthreads();
  for (int off = 1; off < 256; off <<= 1) {
    int x = 0; if (t >= off) x = sh[t - off];
    __syncthreads();
    if (t >= off) sh[t] += x;
    __syncthreads();
  }
  if (t < nb) part[t] = (t == 0) ? 0 : sh[t - 1];
}

__global__ void k_scan3(int* __restrict__ out, const int* __restrict__ part, int n) {
  int i = blockIdx.x * 256 + threadIdx.x;
  if (i < n) out[i] += part[i >> 12];
}

__global__ void k_sentinel(int* __restrict__ p, int v) { *p = v; }

// ---- two-phase bucketed scatter (bucket = 256 consecutive dst nodes) ----
__global__ __launch_bounds__(256) void k_bucketA(
    const int* __restrict__ src, const int* __restrict__ dstv,
    const int* __restrict__ et, int E, const int* __restrict__ off,
    int* __restrict__ bfill, int* __restrict__ tmp, int nbuck) {
  __shared__ int hist[512];
  __shared__ int base[512];
  int t = threadIdx.x;
  int lo = blockIdx.x * ACHUNK;
  int hi = lo + ACHUNK < E ? lo + ACHUNK : E;
  for (int i = t; i < nbuck; i += 256) hist[i] = 0;
  __syncthreads();
  for (int e = lo + t; e < hi; e += 256)
    atomicAdd(&hist[dstv[e] >> 8], 1);
  __syncthreads();
  for (int i = t; i < nbuck; i += 256) {
    int c = hist[i];
    base[i] = c ? (off[i << 8] + atomicAdd(&bfill[i], c)) : 0;
  }
  __syncthreads();
  for (int e = lo + t; e < hi; e += 256) {
    int d = dstv[e];
    int b = d >> 8;
    int pos = atomicAdd(&base[b], 1);
    tmp[pos] = src[e] | (et[e] << 20) | ((d & 255) << 23);
  }
}

__global__ __launch_bounds__(256) void k_bucketB(const int* __restrict__ tmp,
                                                 const int* __restrict__ off,
                                                 int* __restrict__ sps, int N) {
  __shared__ int offs[257];
  __shared__ int fill[256];
  int b = blockIdx.x, t = threadIdx.x;
  int n0 = b << 8;
  int nn = (N - n0) < 256 ? (N - n0) : 256;
  if (t < nn) { offs[t] = off[n0 + t]; fill[t] = 0; }
  if (t == 0) offs[nn] = off[n0 + nn];
  __syncthreads();
  int e0 = offs[0], e1 = offs[nn];
  for (int e = e0 + t; e < e1; e += 256) {
    int v = tmp[e];
    int dl = (v >> 23) & 255;
    int pos = offs[dl] + atomicAdd(&fill[dl], 1);
    sps[pos] = v & 0x7FFFFF;
  }
}

// fallback direct scatter (N > 131072)
__global__ void k_scatter(const int* __restrict__ src, const int* __restrict__ dstv,
                          const int* __restrict__ et, int E,
                          const int* __restrict__ off, int* __restrict__ fill,
                          int* __restrict__ sps) {
  int e = blockIdx.x * 256 + threadIdx.x;
  if (e >= E) return;
  int d = dstv[e];
  int pos = off[d] + atomicAdd(&fill[d], 1);
  sps[pos] = src[e] | (et[e] << 20);
}

// mark nodes whose h2 is read by layer 3: roots + src of root in-edges
__global__ void k_mark(const int* __restrict__ ridx, const int* __restrict__ off,
                       const int* __restrict__ sps, int* __restrict__ mark) {
  int i = blockIdx.x, t = threadIdx.x;
  int n = ridx[i];
  if (t == 0) mark[n] = 1;
  int e0 = off[n], e1 = off[n + 1];
  for (int e = e0 + t; e < e1; e += 64) mark[sps[e] & 0xFFFFF] = 1;
}

// precompute per-(node,type) inverse counts: sinvp[n*8+ty] = 1/max(cnt,1)
__global__ __launch_bounds__(256) void k_sinvp(const int* __restrict__ sps,
                                               const int* __restrict__ off,
                                               float* __restrict__ sinvp, int N) {
  __shared__ int c[16][8];
  int t = threadIdx.x;
  int g = t >> 4, st = t & 15;
  int n = blockIdx.x * 16 + g;
  if (st < 8) c[g][st] = 0;
  __syncthreads();
  if (n < N) {
    int e0 = off[n], e1 = off[n + 1];
    for (int e = e0 + st; e < e1; e += 16)
      atomicAdd(&c[g][((unsigned)sps[e]) >> 20], 1);
  }
  __syncthreads();
  if (n < N && st < 8) {
    int cc = c[g][st];
    sinvp[n * 8 + st] = 1.0f / (float)(cc > 1 ? cc : 1);
  }
}

__global__ void k_f32_to_f16(const float* __restrict__ in, f16* __restrict__ out, int n4) {
  int i = blockIdx.x * 256 + threadIdx.x;
  if (i < n4) {
    float4 v = ((const float4*)in)[i];
    f16x4 o; o[0] = (f16)v.x; o[1] = (f16)v.y; o[2] = (f16)v.z; o[3] = (f16)v.w;
    ((f16x4*)out)[i] = o;
  }
}

// weights for pass p: Wt[row][k], row = cb*PW + j -> source col p*PW+j of chunk cb
// (cb 0..7 = wrel[cb][k][col], cb 8 = wroot[k][col]); pad rows (>= 9*PW) zero.
__global__ void k_tpw(const float* __restrict__ wrel, const float* __restrict__ wroot,
                      f16* __restrict__ dst, int PW, int p) {
  int row = blockIdx.x, k = threadIdx.x;
  float v = 0.f;
  if (row < 9 * PW) {
    int cb = row / PW, j = row - cb * PW;
    int col = p * PW + j;
    v = (cb < 8) ? wrel[(size_t)cb * 16384 + k * 128 + col] : wroot[k * 128 + col];
  }
  dst[(size_t)row * 128 + k] = (f16)v;
}

// ---------------- GEMM: C[M x ncol] = A[M x 128] * Bt^T ----------------
// A f16; B read directly from global (Wt is L2-resident, shared by all blocks);
// only A staged in LDS; epilogue repacked via LDS for f16x8 coalesced stores.
// grid = dim3(col_tiles, row_tiles): consecutive blocks share the A tile.
__global__ __launch_bounds__(256, 4) void k_gemm2(const f16* __restrict__ A,
                                                  const f16* __restrict__ Bt,
                                                  f16* __restrict__ C, int M, int ncol) {
  __shared__ f16 As[128 * 136];
  int tid = threadIdx.x;
  int m0 = blockIdx.y * 128, n0 = blockIdx.x * 128;
#pragma unroll
  for (int cch = 0; cch < 8; cch++) {
    int ci = tid + cch * 256;       // 0..2047
    int row = ci >> 4, c8 = ci & 15;
    int gm = m0 + row;
    f16x8 va = {};
    if (gm < M) va = *(const f16x8*)(A + (size_t)gm * 128 + c8 * 8);
    *(f16x8*)(As + row * 136 + c8 * 8) = va;
  }
  __syncthreads();
  int wid = tid >> 6, lane = tid & 63;
  int wm = (wid & 1) * 64, wn = (wid >> 1) * 64;
  int lm = lane & 15, lk = lane >> 4;
  f32x4 acc[4][4] = {};
#pragma unroll
  for (int ks = 0; ks < 4; ks++) {
    int k0 = ks * 32;
    f16x8 a[4], b[4];
#pragma unroll
    for (int j = 0; j < 4; j++)
      b[j] = *(const f16x8*)(Bt + (size_t)(n0 + wn + j * 16 + lm) * 128 + k0 + lk * 8);
#pragma unroll
    for (int i = 0; i < 4; i++)
      a[i] = *(const f16x8*)(As + (wm + i * 16 + lm) * 136 + k0 + lk * 8);
#pragma unroll
    for (int i = 0; i < 4; i++)
#pragma unroll
      for (int j = 0; j < 4; j++)
        acc[i][j] = __builtin_amdgcn_mfma_f32_16x16x32_f16(a[i], b[j], acc[i][j], 0, 0, 0);
  }
  // epilogue: repack through LDS (As is dead), coalesced f16x8 stores
  __syncthreads();
  f16* H = As;   // [128][136]
#pragma unroll
  for (int i = 0; i < 4; i++)
#pragma unroll
    for (int j = 0; j < 4; j++)
#pragma unroll
      for (int q = 0; q < 4; q++)
        H[(wm + i * 16 + lk * 4 + q) * 136 + wn + j * 16 + lm] = (f16)acc[i][j][q];
  __syncthreads();
  for (int i = tid; i < 128 * 16; i += 256) {
    int row = i >> 4, c8 = i & 15;
    int gm = m0 + row, gn = n0 + c8 * 8;
    if (gm < M && gn < ncol)
      *(f16x8*)(C + (size_t)gm * ncol + gn) = *(const f16x8*)(H + row * 136 + c8 * 8);
  }
}

// ---------------- vectorized edge aggregation for one column pass ----------------
// 256 threads = 16 subgroups of 16 lanes; subgroup g handles node blockIdx*16+g.
template <int PW>
__global__ __launch_bounds__(256) void k_edge_v(
    const f16* __restrict__ Y, const int* __restrict__ sps,
    const int* __restrict__ off, const float* __restrict__ sinvp,
    const float* __restrict__ bias, f16* __restrict__ hout,
    const int* __restrict__ mark, int N, int pass) {
  constexpr int CPL = PW / 16;
  constexpr int LDY = 9 * PW;
  int t = threadIdx.x;
  int g = t >> 4, st = t & 15;
  int n = blockIdx.x * 16 + g;
  if (n >= N) return;
  if (mark && !mark[n]) return;
  float sv = (st < 8) ? sinvp[n * 8 + st] : 0.f;
  int e0 = off[n], e1 = off[n + 1];
  float a[CPL], b2[CPL];
  {
    const f16* rp = Y + (size_t)n * LDY + 8 * PW + st * CPL;
    const float* bp = bias + pass * PW + st * CPL;
#pragma unroll
    for (int q = 0; q < CPL; q++) { a[q] = (float)rp[q] + bp[q]; b2[q] = 0.f; }
  }
  int sgbase = t & 48;
  int e = e0;
  for (; e + 1 < e1; e += 2) {
    int p0 = sps[e], p1 = sps[e + 1];
    int s0 = p0 & 0xFFFFF, ty0 = ((unsigned)p0) >> 20;
    int s1 = p1 & 0xFFFFF, ty1 = ((unsigned)p1) >> 20;
    float sc0 = __shfl(sv, sgbase | ty0);
    float sc1 = __shfl(sv, sgbase | ty1);
    const f16* q0 = Y + (size_t)s0 * LDY + ty0 * PW + st * CPL;
    const f16* q1 = Y + (size_t)s1 * LDY + ty1 * PW + st * CPL;
    if constexpr (PW == 64) {
      f16x4 v0 = *(const f16x4*)q0;
      f16x4 v1 = *(const f16x4*)q1;
      a[0] += (float)v0[0] * sc0; a[1] += (float)v0[1] * sc0;
      a[2] += (float)v0[2] * sc0; a[3] += (float)v0[3] * sc0;
      b2[0] += (float)v1[0] * sc1; b2[1] += (float)v1[1] * sc1;
      b2[2] += (float)v1[2] * sc1; b2[3] += (float)v1[3] * sc1;
    } else {
      f16x2 v0 = *(const f16x2*)q0;
      f16x2 v1 = *(const f16x2*)q1;
      a[0] += (float)v0[0] * sc0; a[1] += (float)v0[1] * sc0;
      b2[0] += (float)v1[0] * sc1; b2[1] += (float)v1[1] * sc1;
    }
  }
  if (e < e1) {
    int p0 = sps[e];
    int s0 = p0 & 0xFFFFF, ty0 = ((unsigned)p0) >> 20;
    float sc0 = __shfl(sv, sgbase | ty0);
    const f16* q0 = Y + (size_t)s0 * LDY + ty0 * PW + st * CPL;
    if constexpr (PW == 64) {
      f16x4 v0 = *(const f16x4*)q0;
      a[0] += (float)v0[0] * sc0; a[1] += (float)v0[1] * sc0;
      a[2] += (float)v0[2] * sc0; a[3] += (float)v0[3] * sc0;
    } else {
      f16x2 v0 = *(const f16x2*)q0;
      a[0] += (float)v0[0] * sc0; a[1] += (float)v0[1] * sc0;
    }
  }
  if constexpr (PW == 64) {
    f16x4 o;
#pragma unroll
    for (int q = 0; q < 4; q++) o[q] = (f16)fmaxf(a[q] + b2[q], 0.f);
    *(f16x4*)(hout + (size_t)n * 128 + pass * PW + st * 4) = o;
  } else {
    f16x2 o;
#pragma unroll
    for (int q = 0; q < 2; q++) o[q] = (f16)fmaxf(a[q] + b2[q], 0.f);
    *(f16x2*)(hout + (size_t)n * 128 + pass * PW + st * 2) = o;
  }
}

// ---------------- layer 3: only at root rows, weights in LDS ----------------
__global__ __launch_bounds__(128) void k_layer3(const f16* __restrict__ h2,
                                                const int* __restrict__ sps,
                                                const int* __restrict__ off,
                                                const float* __restrict__ sinvp,
                                                const int* __restrict__ ridx,
                                                const float* __restrict__ wrel,
                                                const float* __restrict__ wroot,
                                                const float* __restrict__ b3,
                                                float* __restrict__ out) {
  __shared__ f16 W[9 * 2048];   // 0..7 = wrel3[r][k][c], 8 = root3[k][c]
  __shared__ float red[2][16];
  __shared__ float sinv_s[8];
  int t = threadIdx.x;
  int n = ridx[blockIdx.x];
  for (int j = t; j < 9 * 2048; j += 128)
    W[j] = (f16)((j < 8 * 2048) ? wrel[j] : wroot[j - 8 * 2048]);
  if (t < 8) sinv_s[t] = sinvp[n * 8 + t];
  __syncthreads();
  int e0 = off[n], e1 = off[n + 1];
  int c = t & 15, kg = t >> 4;   // 8 k-groups of 16
  float a = 0.f;
  for (int e = e0; e < e1; e++) {
    int ps = sps[e];
    int s = ps & 0xFFFFF, ty = ((unsigned)ps) >> 20;
    float p = 0.f;
#pragma unroll
    for (int j = 0; j < 16; j++) {
      int k = kg * 16 + j;
      p += (float)h2[(size_t)s * 128 + k] * (float)W[ty * 2048 + k * 16 + c];
    }
    a += sinv_s[ty] * p;
  }
  {
    float p = 0.f;
#pragma unroll
    for (int j = 0; j < 16; j++) {
      int k = kg * 16 + j;
      p += (float)h2[(size_t)n * 128 + k] * (float)W[8 * 2048 + k * 16 + c];
    }
    a += p;
  }
  a += __shfl_xor(a, 16);
  a += __shfl_xor(a, 32);
  if ((t & 63) < 16) red[t >> 6][t & 15] = a;
  __syncthreads();
  if (t < 16) out[(size_t)blockIdx.x * 16 + t] = red[0][t] + red[1][t] + b3[t];
}

// ---------------- host ----------------
extern "C" void kernel_launch(void* const* d_in, const int* in_sizes, int n_in,
                              void* d_out, int out_size, void* d_ws, size_t ws_size,
                              hipStream_t stream) {
  const float* x     = (const float*)d_in[0];
  const int*   eidx  = (const int*)d_in[1];
  const int*   etyp  = (const int*)d_in[2];
  const int*   ridx  = (const int*)d_in[3];
  const float* wrel1 = (const float*)d_in[4];
  const float* root1 = (const float*)d_in[5];
  const float* b1    = (const float*)d_in[6];
  const float* wrel2 = (const float*)d_in[7];
  const float* root2 = (const float*)d_in[8];
  const float* b2    = (const float*)d_in[9];
  const float* wrel3 = (const float*)d_in[10];
  const float* root3 = (const float*)d_in[11];
  const float* b3    = (const float*)d_in[12];

  int N = in_sizes[0] / 128;
  int E = in_sizes[2];
  int NROOT = in_sizes[3];
  const int* esrc = eidx;
  const int* edst = eidx + E;

  char* p = (char*)d_ws;
  auto alloc = [&](size_t bytes) { void* r = (void*)p; p += (bytes + 255) & ~(size_t)255; return r; };
  int*   off   = (int*)alloc((size_t)(N + 1) * 4);
  int*   sps   = (int*)alloc((size_t)E * 4);
  f16*   h1    = (f16*)alloc((size_t)N * 128 * 2);
  f16*   h2    = (f16*)alloc((size_t)N * 128 * 2);   // also holds f16(x) for layer 1
  int*   mark  = (int*)alloc((size_t)N * 4);
  float* sinvp = (float*)alloc((size_t)N * 8 * 4);
  f16*   Wt    = (f16*)alloc((size_t)640 * 128 * 2);   // max 5 col-tiles, zero-padded

  size_t used = (size_t)(p - (char*)d_ws);
  size_t remain = ws_size > used ? ws_size - used : 0;
  int PW = (remain >= (size_t)N * 9 * 64 * 2 + (1u << 20)) ? 64 : 32;
  int ldy = 9 * PW;
  f16* Y = (f16*)alloc((size_t)N * ldy * 2);
  // setup-only scratch lives in Y's region (dead until first GEMM writes Y):
  int* tmp   = (int*)Y;            // E ints (phase-A bucket-grouped edges)
  int* bfill = tmp + E;            // 512 ints
  int* part  = bfill + 512;        // 4096 ints (scan partials)
  int* fill  = part + 4096;        // N ints (fallback scatter only)

  int eb = (E + 255) / 256;
  hipMemsetAsync(off, 0, (size_t)(N + 1) * 4, stream);
  hipMemsetAsync(bfill, 0, 512 * 4, stream);
  hipMemsetAsync(mark, 0, (size_t)N * 4, stream);
  k_hist<<<eb, 256, 0, stream>>>(edst, E, off);
  int nb1 = (N + 4095) / 4096;   // 25
  k_scan1<<<nb1, 256, 0, stream>>>(off, off, part, N);
  k_scan2<<<1, 256, 0, stream>>>(part, nb1);
  k_scan3<<<(N + 255) / 256, 256, 0, stream>>>(off, part, N);
  k_sentinel<<<1, 1, 0, stream>>>(off + N, E);

  int nbuck = (N + 255) >> 8;
  if (nbuck <= 512) {
    int nbA = (E + ACHUNK - 1) / ACHUNK;
    k_bucketA<<<nbA, 256, 0, stream>>>(esrc, edst, etyp, E, off, bfill, tmp, nbuck);
    k_bucketB<<<nbuck, 256, 0, stream>>>(tmp, off, sps, N);
  } else {
    hipMemsetAsync(fill, 0, (size_t)N * 4, stream);
    k_scatter<<<eb, 256, 0, stream>>>(esrc, edst, etyp, E, off, fill, sps);
  }
  k_mark<<<NROOT, 64, 0, stream>>>(ridx, off, sps, mark);
  int ng16 = (N + 15) / 16;
  k_sinvp<<<ng16, 256, 0, stream>>>(sps, off, sinvp, N);
  k_f32_to_f16<<<((N * 32) + 255) / 256, 256, 0, stream>>>(x, h2, N * 32);

  int mb = (N + 127) / 128;
  int NT = (ldy + 127) / 128;        // 5 (PW=64) or 3 (PW=32)
  int npass = 128 / PW;

  // layer 1: A = f16(x) (aliased in h2)
  for (int ps = 0; ps < npass; ps++) {
    k_tpw<<<NT * 128, 128, 0, stream>>>(wrel1, root1, Wt, PW, ps);
    k_gemm2<<<dim3(NT, mb), 256, 0, stream>>>(h2, Wt, Y, N, ldy);
    if (PW == 64)
      k_edge_v<64><<<ng16, 256, 0, stream>>>(Y, sps, off, sinvp, b1, h1, nullptr, N, ps);
    else
      k_edge_v<32><<<ng16, 256, 0, stream>>>(Y, sps, off, sinvp, b1, h1, nullptr, N, ps);
  }
  // layer 2: A = h1, edge pass pruned to marked nodes (writes h2 at those rows;
  // layer 3 reads exactly the marked rows)
  for (int ps = 0; ps < npass; ps++) {
    k_tpw<<<NT * 128, 128, 0, stream>>>(wrel2, root2, Wt, PW, ps);
    k_gemm2<<<dim3(NT, mb), 256, 0, stream>>>(h1, Wt, Y, N, ldy);
    if (PW == 64)
      k_edge_v<64><<<ng16, 256, 0, stream>>>(Y, sps, off, sinvp, b2, h2, mark, N, ps);
    else
      k_edge_v<32><<<ng16, 256, 0, stream>>>(Y, sps, off, sinvp, b2, h2, mark, N, ps);
  }
  k_layer3<<<NROOT, 128, 0, stream>>>(h2, sps, off, sinvp, ridx, wrel3, root3, b3,
                                      (float*)d_out);
}

// Round 9
// 487.842 us; speedup vs baseline: 6.1643x; 1.1265x over previous
//
#include <hip/hip_runtime.h>
#include <hip/hip_fp16.h>

// RGCN 3-layer, transform-first with column-split passes:
//   Y = A @ [W_0..W_7, W_root] restricted to output cols [p*PW,(p+1)*PW)
//   h[n, cols] = relu( Y[n,rootblk] + sum_e (1/cnt[n,ty]) * Y[src_e, ty-blk] + bias )
// Edge sort: bucket pipeline only (bucket = 256 dst nodes): coarse bucket hist
// (LDS-privatized) -> bucket scan -> bucket-grouped tmp -> per-bucket exact
// count+scan+scatter (also emits node-level off[]). No N-wide global histogram
// (write-allocate thrash). sinvp precomputed. Edge pass: 16-lane subgroups,
// f16x4 vector gather, shfl sinv broadcast. GEMM: A-only LDS staging, f16x8
// repack epilogue. Layer-2 pruned to marked nodes; layer 3 only at root rows.

typedef _Float16 f16;
typedef _Float16 f16x2 __attribute__((ext_vector_type(2)));
typedef _Float16 f16x4 __attribute__((ext_vector_type(4)));
typedef _Float16 f16x8 __attribute__((ext_vector_type(8)));
typedef float f32x4 __attribute__((ext_vector_type(4)));

#define NREL 8
#define ACHUNK 8192

// ---------------- fallback setup kernels (N > 131072 only) ----------------
__global__ void k_hist(const int* __restrict__ dst, int E, int* __restrict__ cnt) {
  int e = blockIdx.x * 256 + threadIdx.x;
  if (e < E) atomicAdd(&cnt[dst[e]], 1);
}

__global__ void k_scan1(const int* __restrict__ in, int* __restrict__ out,
                        int* __restrict__ part, int n) {
  __shared__ int sh[256];
  int b = blockIdx.x, t = threadIdx.x;
  int base = b * 4096 + t * 16;
  int v[16]; int s = 0;
#pragma unroll
  for (int j = 0; j < 16; j++) { int idx = base + j; int x = (idx < n) ? in[idx] : 0; v[j] = s; s += x; }
  sh[t] = s; __syncthreads();
  for (int off = 1; off < 256; off <<= 1) {
    int x = 0; if (t >= off) x = sh[t - off];
    __syncthreads();
    if (t >= off) sh[t] += x;
    __syncthreads();
  }
  int excl = (t == 0) ? 0 : sh[t - 1];
  if (t == 255) part[b] = sh[255];
#pragma unroll
  for (int j = 0; j < 16; j++) { int idx = base + j; if (idx < n) out[idx] = v[j] + excl; }
}

__global__ void k_scan2(int* __restrict__ part, int nb) {
  __shared__ int sh[256];
  int t = threadIdx.x;
  sh[t] = (t < nb) ? part[t] : 0; __syncthreads();
  for (int off = 1; off < 256; off <<= 1) {
    int x = 0; if (t >= off) x = sh[t - off];
    __syncthreads();
    if (t >= off) sh[t] += x;
    __syncthreads();
  }
  if (t < nb) part[t] = (t == 0) ? 0 : sh[t - 1];
}

__global__ void k_scan3(int* __restrict__ out, const int* __restrict__ part, int n) {
  int i = blockIdx.x * 256 + threadIdx.x;
  if (i < n) out[i] += part[i >> 12];
}

__global__ void k_scatter(const int* __restrict__ src, const int* __restrict__ dstv,
                          const int* __restrict__ et, int E,
                          const int* __restrict__ off, int* __restrict__ fill,
                          int* __restrict__ sps) {
  int e = blockIdx.x * 256 + threadIdx.x;
  if (e >= E) return;
  int d = dstv[e];
  int pos = off[d] + atomicAdd(&fill[d], 1);
  sps[pos] = src[e] | (et[e] << 20);
}

__global__ void k_sentinel(int* __restrict__ p, int v) { *p = v; }

// ---------------- bucket pipeline (bucket = 256 consecutive dst nodes) ----------
// coarse bucket histogram, LDS-privatized
__global__ __launch_bounds__(256) void k_bhist(const int* __restrict__ dstv, int E,
                                               int* __restrict__ bcnt, int nbuck) {
  __shared__ int h[512];
  int t = threadIdx.x;
  for (int i = t; i < 512; i += 256) h[i] = 0;
  __syncthreads();
  int lo = blockIdx.x * ACHUNK;
  int hi = lo + ACHUNK < E ? lo + ACHUNK : E;
  for (int e = lo + t; e < hi; e += 256) atomicAdd(&h[dstv[e] >> 8], 1);
  __syncthreads();
  for (int i = t; i < nbuck; i += 256)
    if (h[i]) atomicAdd(&bcnt[i], h[i]);
}

// single-block scan of bucket counts -> boff[0..nbuck]
__global__ __launch_bounds__(512) void k_bscan(const int* __restrict__ bcnt,
                                               int* __restrict__ boff, int nbuck) {
  __shared__ int sh[512];
  int t = threadIdx.x;
  sh[t] = (t < nbuck) ? bcnt[t] : 0;
  __syncthreads();
  for (int o = 1; o < 512; o <<= 1) {
    int v = 0; if (t >= o) v = sh[t - o];
    __syncthreads();
    sh[t] += v;
    __syncthreads();
  }
  if (t <= nbuck && t < 512) boff[t] = (t == 0) ? 0 : sh[t - 1];
  if (t == 511 && nbuck >= 512) boff[nbuck] = sh[511];
}

// Phase A: chunk of edges -> bucket-grouped tmp (payload src|ty<<20|dstlocal<<23)
__global__ __launch_bounds__(256) void k_bucketA(
    const int* __restrict__ src, const int* __restrict__ dstv,
    const int* __restrict__ et, int E, const int* __restrict__ boff,
    int* __restrict__ bfill, int* __restrict__ tmp, int nbuck) {
  __shared__ int hist[512];
  __shared__ int base[512];
  int t = threadIdx.x;
  int lo = blockIdx.x * ACHUNK;
  int hi = lo + ACHUNK < E ? lo + ACHUNK : E;
  for (int i = t; i < nbuck; i += 256) hist[i] = 0;
  __syncthreads();
  for (int e = lo + t; e < hi; e += 256)
    atomicAdd(&hist[dstv[e] >> 8], 1);
  __syncthreads();
  for (int i = t; i < nbuck; i += 256) {
    int c = hist[i];
    base[i] = c ? (boff[i] + atomicAdd(&bfill[i], c)) : 0;
  }
  __syncthreads();
  for (int e = lo + t; e < hi; e += 256) {
    int d = dstv[e];
    int b = d >> 8;
    int pos = atomicAdd(&base[b], 1);
    tmp[pos] = src[e] | (et[e] << 20) | ((d & 255) << 23);
  }
}

// Phase B: per-bucket node count + scan (emits off[]) + exact scatter into sps
__global__ __launch_bounds__(256) void k_bucketB2(const int* __restrict__ tmp,
                                                  const int* __restrict__ boff,
                                                  int* __restrict__ off,
                                                  int* __restrict__ sps, int N) {
  __shared__ int cnt[256];
  __shared__ int sh[256];
  __shared__ int loff[257];
  int b = blockIdx.x, t = threadIdx.x;
  int n0 = b << 8;
  int nn = (N - n0) < 256 ? (N - n0) : 256;
  cnt[t] = 0;
  __syncthreads();
  int e0 = boff[b], e1 = boff[b + 1];
  for (int e = e0 + t; e < e1; e += 256)
    atomicAdd(&cnt[(tmp[e] >> 23) & 255], 1);
  __syncthreads();
  sh[t] = cnt[t];
  __syncthreads();
  for (int o = 1; o < 256; o <<= 1) {
    int v = 0; if (t >= o) v = sh[t - o];
    __syncthreads();
    sh[t] += v;
    __syncthreads();
  }
  loff[t] = (t == 0) ? 0 : sh[t - 1];
  if (t == 255) loff[256] = sh[255];
  __syncthreads();
  if (t < nn) off[n0 + t] = e0 + loff[t];
  cnt[t] = 0;   // reuse as fill
  __syncthreads();
  for (int e = e0 + t; e < e1; e += 256) {
    int v = tmp[e];
    int dl = (v >> 23) & 255;
    int pos = e0 + loff[dl] + atomicAdd(&cnt[dl], 1);
    sps[pos] = v & 0x7FFFFF;
  }
}

// mark nodes whose h2 is read by layer 3: roots + src of root in-edges
__global__ void k_mark(const int* __restrict__ ridx, const int* __restrict__ off,
                       const int* __restrict__ sps, int* __restrict__ mark) {
  int i = blockIdx.x, t = threadIdx.x;
  int n = ridx[i];
  if (t == 0) mark[n] = 1;
  int e0 = off[n], e1 = off[n + 1];
  for (int e = e0 + t; e < e1; e += 64) mark[sps[e] & 0xFFFFF] = 1;
}

// precompute per-(node,type) inverse counts: sinvp[n*8+ty] = 1/max(cnt,1)
__global__ __launch_bounds__(256) void k_sinvp(const int* __restrict__ sps,
                                               const int* __restrict__ off,
                                               float* __restrict__ sinvp, int N) {
  __shared__ int c[16][8];
  int t = threadIdx.x;
  int g = t >> 4, st = t & 15;
  int n = blockIdx.x * 16 + g;
  if (st < 8) c[g][st] = 0;
  __syncthreads();
  if (n < N) {
    int e0 = off[n], e1 = off[n + 1];
    for (int e = e0 + st; e < e1; e += 16)
      atomicAdd(&c[g][((unsigned)sps[e]) >> 20], 1);
  }
  __syncthreads();
  if (n < N && st < 8) {
    int cc = c[g][st];
    sinvp[n * 8 + st] = 1.0f / (float)(cc > 1 ? cc : 1);
  }
}

__global__ void k_f32_to_f16(const float* __restrict__ in, f16* __restrict__ out, int n4) {
  int i = blockIdx.x * 256 + threadIdx.x;
  if (i < n4) {
    float4 v = ((const float4*)in)[i];
    f16x4 o; o[0] = (f16)v.x; o[1] = (f16)v.y; o[2] = (f16)v.z; o[3] = (f16)v.w;
    ((f16x4*)out)[i] = o;
  }
}

// weights for pass p: Wt[row][k], row = cb*PW + j -> source col p*PW+j of chunk cb
__global__ void k_tpw(const float* __restrict__ wrel, const float* __restrict__ wroot,
                      f16* __restrict__ dst, int PW, int p) {
  int row = blockIdx.x, k = threadIdx.x;
  float v = 0.f;
  if (row < 9 * PW) {
    int cb = row / PW, j = row - cb * PW;
    int col = p * PW + j;
    v = (cb < 8) ? wrel[(size_t)cb * 16384 + k * 128 + col] : wroot[k * 128 + col];
  }
  dst[(size_t)row * 128 + k] = (f16)v;
}

// ---------------- GEMM: C[M x ncol] = A[M x 128] * Bt^T ----------------
__global__ __launch_bounds__(256, 4) void k_gemm2(const f16* __restrict__ A,
                                                  const f16* __restrict__ Bt,
                                                  f16* __restrict__ C, int M, int ncol) {
  __shared__ f16 As[128 * 136];
  int tid = threadIdx.x;
  int m0 = blockIdx.y * 128, n0 = blockIdx.x * 128;
#pragma unroll
  for (int cch = 0; cch < 8; cch++) {
    int ci = tid + cch * 256;
    int row = ci >> 4, c8 = ci & 15;
    int gm = m0 + row;
    f16x8 va = {};
    if (gm < M) va = *(const f16x8*)(A + (size_t)gm * 128 + c8 * 8);
    *(f16x8*)(As + row * 136 + c8 * 8) = va;
  }
  __syncthreads();
  int wid = tid >> 6, lane = tid & 63;
  int wm = (wid & 1) * 64, wn = (wid >> 1) * 64;
  int lm = lane & 15, lk = lane >> 4;
  f32x4 acc[4][4] = {};
#pragma unroll
  for (int ks = 0; ks < 4; ks++) {
    int k0 = ks * 32;
    f16x8 a[4], b[4];
#pragma unroll
    for (int j = 0; j < 4; j++)
      b[j] = *(const f16x8*)(Bt + (size_t)(n0 + wn + j * 16 + lm) * 128 + k0 + lk * 8);
#pragma unroll
    for (int i = 0; i < 4; i++)
      a[i] = *(const f16x8*)(As + (wm + i * 16 + lm) * 136 + k0 + lk * 8);
#pragma unroll
    for (int i = 0; i < 4; i++)
#pragma unroll
      for (int j = 0; j < 4; j++)
        acc[i][j] = __builtin_amdgcn_mfma_f32_16x16x32_f16(a[i], b[j], acc[i][j], 0, 0, 0);
  }
  __syncthreads();
  f16* H = As;
#pragma unroll
  for (int i = 0; i < 4; i++)
#pragma unroll
    for (int j = 0; j < 4; j++)
#pragma unroll
      for (int q = 0; q < 4; q++)
        H[(wm + i * 16 + lk * 4 + q) * 136 + wn + j * 16 + lm] = (f16)acc[i][j][q];
  __syncthreads();
  for (int i = tid; i < 128 * 16; i += 256) {
    int row = i >> 4, c8 = i & 15;
    int gm = m0 + row, gn = n0 + c8 * 8;
    if (gm < M && gn < ncol)
      *(f16x8*)(C + (size_t)gm * ncol + gn) = *(const f16x8*)(H + row * 136 + c8 * 8);
  }
}

// ---------------- vectorized edge aggregation for one column pass ----------------
template <int PW>
__global__ __launch_bounds__(256) void k_edge_v(
    const f16* __restrict__ Y, const int* __restrict__ sps,
    const int* __restrict__ off, const float* __restrict__ sinvp,
    const float* __restrict__ bias, f16* __restrict__ hout,
    const int* __restrict__ mark, int N, int pass) {
  constexpr int CPL = PW / 16;
  constexpr int LDY = 9 * PW;
  int t = threadIdx.x;
  int g = t >> 4, st = t & 15;
  int n = blockIdx.x * 16 + g;
  if (n >= N) return;
  if (mark && !mark[n]) return;
  float sv = (st < 8) ? sinvp[n * 8 + st] : 0.f;
  int e0 = off[n], e1 = off[n + 1];
  float a[CPL], b2[CPL];
  {
    const f16* rp = Y + (size_t)n * LDY + 8 * PW + st * CPL;
    const float* bp = bias + pass * PW + st * CPL;
#pragma unroll
    for (int q = 0; q < CPL; q++) { a[q] = (float)rp[q] + bp[q]; b2[q] = 0.f; }
  }
  int sgbase = t & 48;
  int e = e0;
  for (; e + 1 < e1; e += 2) {
    int p0 = sps[e], p1 = sps[e + 1];
    int s0 = p0 & 0xFFFFF, ty0 = ((unsigned)p0) >> 20;
    int s1 = p1 & 0xFFFFF, ty1 = ((unsigned)p1) >> 20;
    float sc0 = __shfl(sv, sgbase | ty0);
    float sc1 = __shfl(sv, sgbase | ty1);
    const f16* q0 = Y + (size_t)s0 * LDY + ty0 * PW + st * CPL;
    const f16* q1 = Y + (size_t)s1 * LDY + ty1 * PW + st * CPL;
    if constexpr (PW == 64) {
      f16x4 v0 = *(const f16x4*)q0;
      f16x4 v1 = *(const f16x4*)q1;
      a[0] += (float)v0[0] * sc0; a[1] += (float)v0[1] * sc0;
      a[2] += (float)v0[2] * sc0; a[3] += (float)v0[3] * sc0;
      b2[0] += (float)v1[0] * sc1; b2[1] += (float)v1[1] * sc1;
      b2[2] += (float)v1[2] * sc1; b2[3] += (float)v1[3] * sc1;
    } else {
      f16x2 v0 = *(const f16x2*)q0;
      f16x2 v1 = *(const f16x2*)q1;
      a[0] += (float)v0[0] * sc0; a[1] += (float)v0[1] * sc0;
      b2[0] += (float)v1[0] * sc1; b2[1] += (float)v1[1] * sc1;
    }
  }
  if (e < e1) {
    int p0 = sps[e];
    int s0 = p0 & 0xFFFFF, ty0 = ((unsigned)p0) >> 20;
    float sc0 = __shfl(sv, sgbase | ty0);
    const f16* q0 = Y + (size_t)s0 * LDY + ty0 * PW + st * CPL;
    if constexpr (PW == 64) {
      f16x4 v0 = *(const f16x4*)q0;
      a[0] += (float)v0[0] * sc0; a[1] += (float)v0[1] * sc0;
      a[2] += (float)v0[2] * sc0; a[3] += (float)v0[3] * sc0;
    } else {
      f16x2 v0 = *(const f16x2*)q0;
      a[0] += (float)v0[0] * sc0; a[1] += (float)v0[1] * sc0;
    }
  }
  if constexpr (PW == 64) {
    f16x4 o;
#pragma unroll
    for (int q = 0; q < 4; q++) o[q] = (f16)fmaxf(a[q] + b2[q], 0.f);
    *(f16x4*)(hout + (size_t)n * 128 + pass * PW + st * 4) = o;
  } else {
    f16x2 o;
#pragma unroll
    for (int q = 0; q < 2; q++) o[q] = (f16)fmaxf(a[q] + b2[q], 0.f);
    *(f16x2*)(hout + (size_t)n * 128 + pass * PW + st * 2) = o;
  }
}

// ---------------- layer 3: only at root rows, weights in LDS ----------------
__global__ __launch_bounds__(128) void k_layer3(const f16* __restrict__ h2,
                                                const int* __restrict__ sps,
                                                const int* __restrict__ off,
                                                const float* __restrict__ sinvp,
                                                const int* __restrict__ ridx,
                                                const float* __restrict__ wrel,
                                                const float* __restrict__ wroot,
                                                const float* __restrict__ b3,
                                                float* __restrict__ out) {
  __shared__ f16 W[9 * 2048];
  __shared__ float red[2][16];
  __shared__ float sinv_s[8];
  int t = threadIdx.x;
  int n = ridx[blockIdx.x];
  for (int j = t; j < 9 * 2048; j += 128)
    W[j] = (f16)((j < 8 * 2048) ? wrel[j] : wroot[j - 8 * 2048]);
  if (t < 8) sinv_s[t] = sinvp[n * 8 + t];
  __syncthreads();
  int e0 = off[n], e1 = off[n + 1];
  int c = t & 15, kg = t >> 4;
  float a = 0.f;
  for (int e = e0; e < e1; e++) {
    int ps = sps[e];
    int s = ps & 0xFFFFF, ty = ((unsigned)ps) >> 20;
    float p = 0.f;
#pragma unroll
    for (int j = 0; j < 16; j++) {
      int k = kg * 16 + j;
      p += (float)h2[(size_t)s * 128 + k] * (float)W[ty * 2048 + k * 16 + c];
    }
    a += sinv_s[ty] * p;
  }
  {
    float p = 0.f;
#pragma unroll
    for (int j = 0; j < 16; j++) {
      int k = kg * 16 + j;
      p += (float)h2[(size_t)n * 128 + k] * (float)W[8 * 2048 + k * 16 + c];
    }
    a += p;
  }
  a += __shfl_xor(a, 16);
  a += __shfl_xor(a, 32);
  if ((t & 63) < 16) red[t >> 6][t & 15] = a;
  __syncthreads();
  if (t < 16) out[(size_t)blockIdx.x * 16 + t] = red[0][t] + red[1][t] + b3[t];
}

// ---------------- host ----------------
extern "C" void kernel_launch(void* const* d_in, const int* in_sizes, int n_in,
                              void* d_out, int out_size, void* d_ws, size_t ws_size,
                              hipStream_t stream) {
  const float* x     = (const float*)d_in[0];
  const int*   eidx  = (const int*)d_in[1];
  const int*   etyp  = (const int*)d_in[2];
  const int*   ridx  = (const int*)d_in[3];
  const float* wrel1 = (const float*)d_in[4];
  const float* root1 = (const float*)d_in[5];
  const float* b1    = (const float*)d_in[6];
  const float* wrel2 = (const float*)d_in[7];
  const float* root2 = (const float*)d_in[8];
  const float* b2    = (const float*)d_in[9];
  const float* wrel3 = (const float*)d_in[10];
  const float* root3 = (const float*)d_in[11];
  const float* b3    = (const float*)d_in[12];

  int N = in_sizes[0] / 128;
  int E = in_sizes[2];
  int NROOT = in_sizes[3];
  const int* esrc = eidx;
  const int* edst = eidx + E;

  char* p = (char*)d_ws;
  auto alloc = [&](size_t bytes) { void* r = (void*)p; p += (bytes + 255) & ~(size_t)255; return r; };
  int*   off   = (int*)alloc((size_t)(N + 1) * 4);
  int*   sps   = (int*)alloc((size_t)E * 4);
  f16*   h1    = (f16*)alloc((size_t)N * 128 * 2);
  f16*   h2    = (f16*)alloc((size_t)N * 128 * 2);   // also holds f16(x) for layer 1
  int*   mark  = (int*)alloc((size_t)N * 4);
  float* sinvp = (float*)alloc((size_t)N * 8 * 4);
  f16*   Wt    = (f16*)alloc((size_t)640 * 128 * 2);
  int*   bcnt  = (int*)alloc(512 * 4);
  int*   boff  = (int*)alloc(513 * 4);
  int*   bfill = (int*)alloc(512 * 4);

  size_t used = (size_t)(p - (char*)d_ws);
  size_t remain = ws_size > used ? ws_size - used : 0;
  int PW = (remain >= (size_t)N * 9 * 64 * 2 + (1u << 20)) ? 64 : 32;
  int ldy = 9 * PW;
  f16* Y = (f16*)alloc((size_t)N * ldy * 2);
  // setup-only scratch lives in Y's region (dead until first GEMM writes Y):
  int* tmp  = (int*)Y;             // E ints (phase-A bucket-grouped edges)
  int* part = tmp + E;             // 4096 ints (fallback scan partials)
  int* fill = part + 4096;         // N ints (fallback scatter only)

  int nbuck = (N + 255) >> 8;
  int nbA = (E + ACHUNK - 1) / ACHUNK;
  hipMemsetAsync(mark, 0, (size_t)N * 4, stream);

  if (nbuck <= 512) {
    hipMemsetAsync(bcnt, 0, 512 * 4, stream);
    hipMemsetAsync(bfill, 0, 512 * 4, stream);
    k_bhist<<<nbA, 256, 0, stream>>>(edst, E, bcnt, nbuck);
    k_bscan<<<1, 512, 0, stream>>>(bcnt, boff, nbuck);
    k_bucketA<<<nbA, 256, 0, stream>>>(esrc, edst, etyp, E, boff, bfill, tmp, nbuck);
    k_bucketB2<<<nbuck, 256, 0, stream>>>(tmp, boff, off, sps, N);
    k_sentinel<<<1, 1, 0, stream>>>(off + N, E);
  } else {
    int eb = (E + 255) / 256;
    hipMemsetAsync(off, 0, (size_t)(N + 1) * 4, stream);
    hipMemsetAsync(fill, 0, (size_t)N * 4, stream);
    k_hist<<<eb, 256, 0, stream>>>(edst, E, off);
    int nb1 = (N + 4095) / 4096;
    k_scan1<<<nb1, 256, 0, stream>>>(off, off, part, N);
    k_scan2<<<1, 256, 0, stream>>>(part, nb1);
    k_scan3<<<(N + 255) / 256, 256, 0, stream>>>(off, part, N);
    k_sentinel<<<1, 1, 0, stream>>>(off + N, E);
    k_scatter<<<eb, 256, 0, stream>>>(esrc, edst, etyp, E, off, fill, sps);
  }
  k_mark<<<NROOT, 64, 0, stream>>>(ridx, off, sps, mark);
  int ng16 = (N + 15) / 16;
  k_sinvp<<<ng16, 256, 0, stream>>>(sps, off, sinvp, N);
  k_f32_to_f16<<<((N * 32) + 255) / 256, 256, 0, stream>>>(x, h2, N * 32);

  int mb = (N + 127) / 128;
  int NT = (ldy + 127) / 128;
  int npass = 128 / PW;

  // layer 1: A = f16(x) (aliased in h2)
  for (int ps = 0; ps < npass; ps++) {
    k_tpw<<<NT * 128, 128, 0, stream>>>(wrel1, root1, Wt, PW, ps);
    k_gemm2<<<dim3(NT, mb), 256, 0, stream>>>(h2, Wt, Y, N, ldy);
    if (PW == 64)
      k_edge_v<64><<<ng16, 256, 0, stream>>>(Y, sps, off, sinvp, b1, h1, nullptr, N, ps);
    else
      k_edge_v<32><<<ng16, 256, 0, stream>>>(Y, sps, off, sinvp, b1, h1, nullptr, N, ps);
  }
  // layer 2: A = h1, edge pass pruned to marked nodes
  for (int ps = 0; ps < npass; ps++) {
    k_tpw<<<NT * 128, 128, 0, stream>>>(wrel2, root2, Wt, PW, ps);
    k_gemm2<<<dim3(NT, mb), 256, 0, stream>>>(h1, Wt, Y, N, ldy);
    if (PW == 64)
      k_edge_v<64><<<ng16, 256, 0, stream>>>(Y, sps, off, sinvp, b2, h2, mark, N, ps);
    else
      k_edge_v<32><<<ng16, 256, 0, stream>>>(Y, sps, off, sinvp, b2, h2, mark, N, ps);
  }
  k_layer3<<<NROOT, 128, 0, stream>>>(h2, sps, off, sinvp, ridx, wrel3, root3, b3,
                                      (float*)d_out);
}